// Round 3
// baseline (986.276 us; speedup 1.0000x reference)
//
#include <hip/hip_runtime.h>
#include <cmath>

#define B_ 2
#define T_ 4096
#define C_ 2048
#define H_ 32
#define N_ 64
#define L_ 64
#define NC_ 64
#define BT_ 8192

// ---------- storage abstraction: fp32 or bf16-in-memory (compute fp32) ----------
template <typename T> struct io;
template <> struct io<float> {
  static __device__ __forceinline__ float  ld (const float* p) { return *p; }
  static __device__ __forceinline__ float4 ld4(const float* p) { return *(const float4*)p; }
  static __device__ __forceinline__ void st (float* p, float v) { *p = v; }
  static __device__ __forceinline__ void st4(float* p, float4 v) { *(float4*)p = v; }
  // uniform (scalar-pipe) load of 16 row elements into SGPR-resident floats.
  // AS4 (constant) pointer + uniform address => s_load_dwordx8.
  static __device__ __forceinline__ void ld16u(const float* p, float* out) {
    typedef float fv8 __attribute__((ext_vector_type(8)));
    auto cp = (const __attribute__((address_space(4))) fv8*)(unsigned long long)p;
    fv8 a = cp[0];
    fv8 b = cp[1];
#pragma unroll
    for (int j = 0; j < 8; ++j) { out[j] = a[j]; out[8 + j] = b[j]; }
  }
};
template <> struct io<unsigned short> {
  static __device__ __forceinline__ float ld(const unsigned short* p) {
    return __uint_as_float((unsigned)(*p) << 16);
  }
  static __device__ __forceinline__ float4 ld4(const unsigned short* p) {
    ushort4 u = *(const ushort4*)p;
    return make_float4(__uint_as_float((unsigned)u.x << 16),
                       __uint_as_float((unsigned)u.y << 16),
                       __uint_as_float((unsigned)u.z << 16),
                       __uint_as_float((unsigned)u.w << 16));
  }
  static __device__ __forceinline__ unsigned short cvt1(float x) {
    unsigned u = __float_as_uint(x);
    return (unsigned short)((u + 0x7fffu + ((u >> 16) & 1u)) >> 16);
  }
  static __device__ __forceinline__ void st(unsigned short* p, float v) { *p = cvt1(v); }
  static __device__ __forceinline__ void st4(unsigned short* p, float4 v) {
    ushort4 u;
    u.x = cvt1(v.x); u.y = cvt1(v.y); u.z = cvt1(v.z); u.w = cvt1(v.w);
    *(ushort4*)p = u;
  }
  // uniform scalar load of 16 bf16 row elements; unpack on the SALU pipe.
  static __device__ __forceinline__ void ld16u(const unsigned short* p, float* out) {
    typedef unsigned int uv8 __attribute__((ext_vector_type(8)));
    auto cp = (const __attribute__((address_space(4))) uv8*)(unsigned long long)p;
    uv8 u = *cp;
#pragma unroll
    for (int j = 0; j < 8; ++j) {
      out[2 * j]     = __uint_as_float(u[j] << 16);
      out[2 * j + 1] = __uint_as_float(u[j] & 0xffff0000u);
    }
  }
};

// broadcast lane `lane`'s value of v to all lanes (v_readlane, VALU only)
static __device__ __forceinline__ float bcast(float v, int lane) {
  return __uint_as_float(__builtin_amdgcn_readlane(__float_as_uint(v), lane));
}

// ---------------- K0: Z = x + (shift(x) - x) * maa_x ----------------
template <typename ST>
static __global__ __launch_bounds__(256) void k0_z(
    const float* __restrict__ hidden, const float* __restrict__ attn_x,
    const float* __restrict__ maa_x, ST* __restrict__ Z) {
  int idx = blockIdx.x * 256 + threadIdx.x;
  int base = idx * 4;
  int bt = base >> 11;           // / C_
  int c  = base & (C_ - 1);
  int t  = bt & (T_ - 1);
  int b  = bt >> 12;
  float4 x = *(const float4*)(hidden + (size_t)base);
  float4 xp;
  if (t == 0) xp = *(const float4*)(attn_x + (size_t)b * C_ + c);
  else        xp = *(const float4*)(hidden + (size_t)base - C_);
  float4 mx = *(const float4*)(maa_x + c);
  float4 z;
  z.x = x.x + (xp.x - x.x) * mx.x;
  z.y = x.y + (xp.y - x.y) * mx.y;
  z.z = x.z + (xp.z - x.z) * mx.z;
  z.w = x.w + (xp.w - x.w) * mx.w;
  io<ST>::st4(Z + (size_t)base, z);
}

// ---------------- K1: P = tanh(Z @ W1[:, :128]) ----------------
// Readlane-broadcast GEMM: block 256 = 4 waves x 4 tokens, grid 512.
template <typename ST>
static __global__ __launch_bounds__(256) void k1_p(
    const ST* __restrict__ Z, const float* __restrict__ W1,
    float* __restrict__ P) {
  __shared__ float w1s[2][64 * 128];
  int tid = threadIdx.x;
  int lane = tid & 63;
  int wv = tid >> 6;
  int bt0 = blockIdx.x * 16 + wv * 4;
  float acc[4][2];
#pragma unroll
  for (int tk = 0; tk < 4; ++tk) { acc[tk][0] = 0.f; acc[tk][1] = 0.f; }

  // stage chunk 0
#pragma unroll
  for (int q = 0; q < 8; ++q) {
    int idx = q * 256 + tid;            // 0..2047
    int cc = idx >> 5;
    int j4 = (idx & 31) * 4;
    *(float4*)&w1s[0][cc * 128 + j4] = *(const float4*)&W1[(size_t)cc * 160 + j4];
  }
  __syncthreads();

#pragma unroll 1
  for (int ch = 0; ch < 32; ++ch) {
    int c0 = ch * 64;
    int buf = ch & 1;
    float z0 = io<ST>::ld(Z + (size_t)(bt0 + 0) * C_ + c0 + lane);
    float z1 = io<ST>::ld(Z + (size_t)(bt0 + 1) * C_ + c0 + lane);
    float z2 = io<ST>::ld(Z + (size_t)(bt0 + 2) * C_ + c0 + lane);
    float z3 = io<ST>::ld(Z + (size_t)(bt0 + 3) * C_ + c0 + lane);
    if (ch + 1 < 32) {
#pragma unroll
      for (int q = 0; q < 8; ++q) {
        int idx = q * 256 + tid;
        int cc = idx >> 5;
        int j4 = (idx & 31) * 4;
        *(float4*)&w1s[buf ^ 1][cc * 128 + j4] =
            *(const float4*)&W1[(size_t)(c0 + 64 + cc) * 160 + j4];
      }
    }
#pragma unroll
    for (int l = 0; l < 64; ++l) {
      float wa = w1s[buf][l * 128 + lane];
      float wb = w1s[buf][l * 128 + lane + 64];
      float s0 = bcast(z0, l), s1 = bcast(z1, l), s2 = bcast(z2, l), s3 = bcast(z3, l);
      acc[0][0] = fmaf(s0, wa, acc[0][0]); acc[0][1] = fmaf(s0, wb, acc[0][1]);
      acc[1][0] = fmaf(s1, wa, acc[1][0]); acc[1][1] = fmaf(s1, wb, acc[1][1]);
      acc[2][0] = fmaf(s2, wa, acc[2][0]); acc[2][1] = fmaf(s2, wb, acc[2][1]);
      acc[3][0] = fmaf(s3, wa, acc[3][0]); acc[3][1] = fmaf(s3, wb, acc[3][1]);
    }
    __syncthreads();
  }
#pragma unroll
  for (int tk = 0; tk < 4; ++tk) {
    P[(size_t)(bt0 + tk) * 128 + lane]      = tanhf(acc[tk][0]);
    P[(size_t)(bt0 + tk) * 128 + lane + 64] = tanhf(acc[tk][1]);
  }
}

// ---------------- K2: xw/xk/xv/xr = x + xx*(maa_f + P_f @ W2_f) ----------------
template <typename ST>
static __global__ __launch_bounds__(256) void k2_mix(
    const float* __restrict__ hidden, const float* __restrict__ attn_x,
    const float* __restrict__ P, const float* __restrict__ W2,
    const float* __restrict__ maa_w, const float* __restrict__ maa_k,
    const float* __restrict__ maa_v, const float* __restrict__ maa_r,
    ST* __restrict__ XW, ST* __restrict__ XK,
    ST* __restrict__ XV, ST* __restrict__ XR) {
  int cb = blockIdx.x & 7;
  int tb = blockIdx.x >> 3;
  int c = cb * 256 + threadIdx.x;
  int bt0 = tb * 16;
  float xv_[16], xx_[16];
#pragma unroll
  for (int tk = 0; tk < 16; ++tk) {
    int bt = bt0 + tk;
    float x = hidden[(size_t)bt * C_ + c];
    int t = bt & (T_ - 1);
    int b = bt >> 12;
    float xp = (t == 0) ? attn_x[(size_t)b * C_ + c]
                        : hidden[(size_t)(bt - 1) * C_ + c];
    xv_[tk] = x;
    xx_[tk] = xp - x;
  }
#pragma unroll
  for (int f = 0; f < 4; ++f) {
    const float* mp = (f == 0) ? maa_w : (f == 1) ? maa_k : (f == 2) ? maa_v : maa_r;
    ST* op          = (f == 0) ? XW    : (f == 1) ? XK    : (f == 2) ? XV    : XR;
    float w2r[32];
#pragma unroll
    for (int k = 0; k < 32; ++k) w2r[k] = W2[(size_t)(f * 32 + k) * C_ + c];
    float mf = mp[c];
    for (int tk = 0; tk < 16; ++tk) {
      const float4* p4 = (const float4*)(P + (size_t)(bt0 + tk) * 128 + f * 32);
      float a0 = 0.f, a1 = 0.f, a2 = 0.f, a3 = 0.f;
#pragma unroll
      for (int q = 0; q < 8; ++q) {
        float4 pv = p4[q];
        a0 = fmaf(pv.x, w2r[4 * q + 0], a0);
        a1 = fmaf(pv.y, w2r[4 * q + 1], a1);
        a2 = fmaf(pv.z, w2r[4 * q + 2], a2);
        a3 = fmaf(pv.w, w2r[4 * q + 3], a3);
      }
      float acc = (a0 + a1) + (a2 + a3);
      io<ST>::st(op + (size_t)(bt0 + tk) * C_ + c, xv_[tk] + xx_[tk] * (mf + acc));
    }
  }
}

// ---------------- K3: D1 = tanh(XW @ DW1) ----------------
template <typename ST>
static __global__ __launch_bounds__(256) void k3_d1(
    const ST* __restrict__ XW, const float* __restrict__ DW1,
    float* __restrict__ D1) {
  __shared__ float w1s[2][64 * 64];
  int tid = threadIdx.x;
  int lane = tid & 63;
  int wv = tid >> 6;
  int bt0 = blockIdx.x * 16 + wv * 4;
  float acc[4];
#pragma unroll
  for (int tk = 0; tk < 4; ++tk) acc[tk] = 0.f;

#pragma unroll
  for (int q = 0; q < 4; ++q) {
    int idx = q * 256 + tid;            // 0..1023
    int cc = idx >> 4;
    int j4 = (idx & 15) * 4;
    *(float4*)&w1s[0][cc * 64 + j4] = *(const float4*)&DW1[(size_t)cc * 64 + j4];
  }
  __syncthreads();

#pragma unroll 1
  for (int ch = 0; ch < 32; ++ch) {
    int c0 = ch * 64;
    int buf = ch & 1;
    float z0 = io<ST>::ld(XW + (size_t)(bt0 + 0) * C_ + c0 + lane);
    float z1 = io<ST>::ld(XW + (size_t)(bt0 + 1) * C_ + c0 + lane);
    float z2 = io<ST>::ld(XW + (size_t)(bt0 + 2) * C_ + c0 + lane);
    float z3 = io<ST>::ld(XW + (size_t)(bt0 + 3) * C_ + c0 + lane);
    if (ch + 1 < 32) {
#pragma unroll
      for (int q = 0; q < 4; ++q) {
        int idx = q * 256 + tid;
        int cc = idx >> 4;
        int j4 = (idx & 15) * 4;
        *(float4*)&w1s[buf ^ 1][cc * 64 + j4] =
            *(const float4*)&DW1[(size_t)(c0 + 64 + cc) * 64 + j4];
      }
    }
#pragma unroll
    for (int l = 0; l < 64; ++l) {
      float wa = w1s[buf][l * 64 + lane];
      acc[0] = fmaf(bcast(z0, l), wa, acc[0]);
      acc[1] = fmaf(bcast(z1, l), wa, acc[1]);
      acc[2] = fmaf(bcast(z2, l), wa, acc[2]);
      acc[3] = fmaf(bcast(z3, l), wa, acc[3]);
    }
    __syncthreads();
  }
#pragma unroll
  for (int tk = 0; tk < 4; ++tk)
    D1[(size_t)(bt0 + tk) * 64 + lane] = tanhf(acc[tk]);
}

// ---------------- K4: DEC = exp(-exp(time_decay + D1 @ DW2)) ----------------
template <typename ST>
static __global__ __launch_bounds__(256) void k4_decay(
    const float* __restrict__ D1, const float* __restrict__ DW2,
    const float* __restrict__ td, ST* __restrict__ DEC) {
  int cb = blockIdx.x & 7;
  int tb = blockIdx.x >> 3;
  int c = cb * 256 + threadIdx.x;
  int bt0 = tb * 16;
  float w2r[64];
#pragma unroll
  for (int k = 0; k < 64; ++k) w2r[k] = DW2[(size_t)k * C_ + c];
  float tdv = td[c];
  for (int tk = 0; tk < 16; ++tk) {
    const float4* d4 = (const float4*)(D1 + (size_t)(bt0 + tk) * 64);
    float a0 = 0.f, a1 = 0.f, a2 = 0.f, a3 = 0.f;
#pragma unroll
    for (int q = 0; q < 16; ++q) {
      float4 dv = d4[q];
      a0 = fmaf(dv.x, w2r[4 * q + 0], a0);
      a1 = fmaf(dv.y, w2r[4 * q + 1], a1);
      a2 = fmaf(dv.z, w2r[4 * q + 2], a2);
      a3 = fmaf(dv.w, w2r[4 * q + 3], a3);
    }
    float w = tdv + (a0 + a1) + (a2 + a3);
    io<ST>::st(DEC + (size_t)(bt0 + tk) * C_ + c, expf(-expf(w)));
  }
}

// ---------------- K5: intra-chunk recurrence, scalar-pipe broadcast ----------------
// r/k/w rows are wave-uniform. They are loaded through constant-AS (addrspace(4))
// pointers at a readfirstlane-uniform address => s_load_dwordx8 into SGPRs; bf16
// unpack runs on the SALU pipe. Inner loop is 3 VALU ops per (t,n), each v_fma/v_mul
// taking one SGPR operand directly. No LDS round-trip, no readlane.
// XR/XK/DEC are genuinely read-only here (RQ is written over the dead XV buffer),
// so the constant-AS license is honest.
template <typename ST>
static __global__ __launch_bounds__(256) void k5_intra(
    const ST* __restrict__ XR, const ST* __restrict__ XK,
    ST* XVRQ,
    const ST* __restrict__ DEC, const float* __restrict__ faaaa,
    ST* __restrict__ UC, float* __restrict__ DCp, float* __restrict__ Y) {
  int m = threadIdx.x & 63;
  int chunk = __builtin_amdgcn_readfirstlane(blockIdx.x * 4 + (threadIdx.x >> 6));
  int cc = chunk & (NC_ - 1);
  int h = (chunk >> 6) & (H_ - 1);
  int b = chunk >> 11;
  float u = faaaa[h];
  float s[64];
#pragma unroll
  for (int n = 0; n < 64; ++n) s[n] = 0.f;
  float areg = 1.f;
  size_t row = ((size_t)(b * T_ + cc * L_)) * C_ + h * N_;
  for (int t = 0; t < L_; ++t, row += C_) {
    const ST* rrow = XR + row;
    const ST* krow = XK + row;
    const ST* wrow = DEC + row;
    float vm = io<ST>::ld(XVRQ + row + m);
    float rl = io<ST>::ld(rrow + m);
    float kl = io<ST>::ld(krow + m);
    float wl = io<ST>::ld(wrow + m);
    float dot = rl * kl;
#pragma unroll
    for (int mk = 32; mk >= 1; mk >>= 1) dot += __shfl_xor(dot, mk, 64);
    float y0 = u * vm * dot, y1 = 0.f, y2 = 0.f, y3 = 0.f;
#pragma unroll
    for (int g = 0; g < 4; ++g) {
      float rr[16], kk[16], ww[16];
      io<ST>::ld16u(rrow + g * 16, rr);
      io<ST>::ld16u(krow + g * 16, kk);
      io<ST>::ld16u(wrow + g * 16, ww);
#pragma unroll
      for (int j = 0; j < 16; j += 4) {
        int n = g * 16 + j;
        y0 = fmaf(rr[j + 0], s[n + 0], y0); s[n + 0] = fmaf(ww[j + 0], s[n + 0], kk[j + 0] * vm);
        y1 = fmaf(rr[j + 1], s[n + 1], y1); s[n + 1] = fmaf(ww[j + 1], s[n + 1], kk[j + 1] * vm);
        y2 = fmaf(rr[j + 2], s[n + 2], y2); s[n + 2] = fmaf(ww[j + 2], s[n + 2], kk[j + 2] * vm);
        y3 = fmaf(rr[j + 3], s[n + 3], y3); s[n + 3] = fmaf(ww[j + 3], s[n + 3], kk[j + 3] * vm);
      }
    }
    io<ST>::st(XVRQ + row + m, rl * areg);   // RQ = r * cumdecay (pre-step)
    areg *= wl;
    Y[row + m] = (y0 + y1) + (y2 + y3);
  }
  size_t ucb = (size_t)chunk * (N_ * N_);
#pragma unroll
  for (int n = 0; n < 64; ++n) io<ST>::st(UC + ucb + (size_t)n * 64 + m, s[n]);
  DCp[(size_t)chunk * N_ + m] = areg;
}

// ---------------- K6: inter-chunk state scan ----------------
template <typename ST>
static __global__ __launch_bounds__(256) void k6_scan(
    const float* __restrict__ attn_kv, ST* __restrict__ UC,
    const float* __restrict__ DCp) {
  int msel = blockIdx.x & 3;
  int bh = blockIdx.x >> 2;
  int ml = threadIdx.x & 15;
  int n0 = threadIdx.x >> 4;
  int m = msel * 16 + ml;
  float s[4];
#pragma unroll
  for (int i = 0; i < 4; ++i) {
    int n = n0 + 16 * i;
    s[i] = attn_kv[((size_t)bh * N_ + n) * N_ + m];
  }
  for (int c = 0; c < NC_; ++c) {
    size_t cb = (size_t)bh * NC_ + c;
#pragma unroll
    for (int i = 0; i < 4; ++i) {
      int n = n0 + 16 * i;
      size_t idx = (cb * (size_t)(N_ * N_)) + (size_t)n * 64 + m;
      float uc = io<ST>::ld(UC + idx);
      float dc = DCp[cb * N_ + n];
      io<ST>::st(UC + idx, s[i]);
      s[i] = fmaf(dc, s[i], uc);
    }
  }
}

// ---------------- K7: Y += RQ @ s0 (scalar-pipe broadcast) ----------------
// RQ rows wave-uniform, never written here -> s_load into SGPRs; inner loop is a
// single SGPR-operand v_fma per (t,n); the per-lane q vector load is gone.
template <typename ST>
static __global__ __launch_bounds__(256) void k7_state(
    const ST* __restrict__ RQ, const ST* __restrict__ UC,
    float* __restrict__ Y) {
  int m = threadIdx.x & 63;
  int chunk = __builtin_amdgcn_readfirstlane(blockIdx.x * 4 + (threadIdx.x >> 6));
  int cc = chunk & (NC_ - 1);
  int h = (chunk >> 6) & (H_ - 1);
  int b = chunk >> 11;
  float sc[64];
  size_t ucb = (size_t)chunk * (N_ * N_);
#pragma unroll
  for (int n = 0; n < 64; ++n) sc[n] = io<ST>::ld(UC + ucb + (size_t)n * 64 + m);
  size_t row = ((size_t)(b * T_ + cc * L_)) * C_ + h * N_;
  for (int t = 0; t < L_; ++t, row += C_) {
    const ST* qrow = RQ + row;
    float y0 = Y[row + m], y1 = 0.f, y2 = 0.f, y3 = 0.f;
#pragma unroll
    for (int g = 0; g < 4; ++g) {
      float qq[16];
      io<ST>::ld16u(qrow + g * 16, qq);
#pragma unroll
      for (int j = 0; j < 16; j += 4) {
        int n = g * 16 + j;
        y0 = fmaf(qq[j + 0], sc[n + 0], y0);
        y1 = fmaf(qq[j + 1], sc[n + 1], y1);
        y2 = fmaf(qq[j + 2], sc[n + 2], y2);
        y3 = fmaf(qq[j + 3], sc[n + 3], y3);
      }
    }
    Y[row + m] = (y0 + y1) + (y2 + y3);
  }
}

// ---------------- host ----------------
template <typename ST>
static void run_all(void* const* d_in, void* d_out, void* d_ws, hipStream_t stream) {
  const float* hidden = (const float*)d_in[0];
  const float* attn_x = (const float*)d_in[1];
  const float* attn_kv = (const float*)d_in[2];
  const float* maa_x = (const float*)d_in[4];
  const float* maa_w = (const float*)d_in[5];
  const float* maa_k = (const float*)d_in[6];
  const float* maa_v = (const float*)d_in[7];
  const float* maa_r = (const float*)d_in[8];
  const float* W1 = (const float*)d_in[10];
  const float* W2 = (const float*)d_in[11];
  const float* tdec = (const float*)d_in[12];
  const float* DW1 = (const float*)d_in[13];
  const float* DW2 = (const float*)d_in[14];
  const float* faaaa = (const float*)d_in[15];

  const size_t BIG = (size_t)BT_ * C_;          // 16.78M elems
  char* p = (char*)d_ws;
  ST* A   = (ST*)p; p += BIG * sizeof(ST);      // Z -> XW -> DEC
  ST* XK  = (ST*)p; p += BIG * sizeof(ST);
  ST* XV  = (ST*)p; p += BIG * sizeof(ST);      // XV, overwritten by RQ in k5
  ST* XR  = (ST*)p; p += BIG * sizeof(ST);      // XR (read-only in k5)
  ST* UC  = (ST*)p; p += BIG * sizeof(ST);      // B*H*NC*N*N == BT*C elems
  float* P   = (float*)p; p += (size_t)BT_ * 128 * 4;
  float* D1  = (float*)p; p += (size_t)BT_ * 64 * 4;
  float* DCp = (float*)p;
  float* Y = (float*)d_out;

  k0_z<ST>    <<<16384, 256, 0, stream>>>(hidden, attn_x, maa_x, A /*Z*/);
  k1_p<ST>    <<<BT_ / 16, 256, 0, stream>>>(A /*Z*/, W1, P);
  k2_mix<ST>  <<<(BT_ / 16) * 8, 256, 0, stream>>>(hidden, attn_x, P, W2,
                                                   maa_w, maa_k, maa_v, maa_r,
                                                   A /*XW*/, XK, XV, XR);
  k3_d1<ST>   <<<BT_ / 16, 256, 0, stream>>>(A /*XW*/, DW1, D1);
  k4_decay<ST><<<(BT_ / 16) * 8, 256, 0, stream>>>(D1, DW2, tdec, A /*DEC*/);
  k5_intra<ST><<<B_ * H_ * NC_ / 4, 256, 0, stream>>>(XR, XK, XV /*v in, rq out*/,
                                                      A /*DEC*/, faaaa,
                                                      UC, DCp, Y);
  k6_scan<ST> <<<B_ * H_ * 4, 256, 0, stream>>>(attn_kv, UC, DCp);
  k7_state<ST><<<B_ * H_ * NC_ / 4, 256, 0, stream>>>(XV /*RQ*/, UC, Y);
}

extern "C" void kernel_launch(void* const* d_in, const int* in_sizes, int n_in,
                              void* d_out, int out_size, void* d_ws, size_t ws_size,
                              hipStream_t stream) {
  const size_t BIG = (size_t)BT_ * C_;
  const size_t small = (size_t)BT_ * 128 * 4 + (size_t)BT_ * 64 * 4 +
                       (size_t)B_ * H_ * NC_ * N_ * 4;
  const size_t need_f32 = BIG * 4 * 5 + small;   // ~343 MB
  if (ws_size >= need_f32)
    run_all<float>(d_in, d_out, d_ws, stream);
  else
    run_all<unsigned short>(d_in, d_out, d_ws, stream);  // bf16 storage, ~175 MB
}

// Round 4
// 889.713 us; speedup vs baseline: 1.1085x; 1.1085x over previous
//
#include <hip/hip_runtime.h>
#include <cmath>

#define B_ 2
#define T_ 4096
#define C_ 2048
#define H_ 32
#define N_ 64
#define L_ 64
#define NC_ 64
#define BT_ 8192

typedef unsigned short u16;
typedef unsigned int u32;

// ---------- storage abstraction: fp32 or bf16-in-memory (compute fp32) ----------
template <typename T> struct io;
template <> struct io<float> {
  static __device__ __forceinline__ float  ld (const float* p) { return *p; }
  static __device__ __forceinline__ float4 ld4(const float* p) { return *(const float4*)p; }
  static __device__ __forceinline__ void st (float* p, float v) { *p = v; }
  static __device__ __forceinline__ void st4(float* p, float4 v) { *(float4*)p = v; }
};
template <> struct io<u16> {
  static __device__ __forceinline__ float ld(const u16* p) {
    return __uint_as_float((unsigned)(*p) << 16);
  }
  static __device__ __forceinline__ float4 ld4(const u16* p) {
    ushort4 u = *(const ushort4*)p;
    return make_float4(__uint_as_float((unsigned)u.x << 16),
                       __uint_as_float((unsigned)u.y << 16),
                       __uint_as_float((unsigned)u.z << 16),
                       __uint_as_float((unsigned)u.w << 16));
  }
  static __device__ __forceinline__ u16 cvt1(float x) {
    unsigned u = __float_as_uint(x);
    return (u16)((u + 0x7fffu + ((u >> 16) & 1u)) >> 16);
  }
  static __device__ __forceinline__ void st(u16* p, float v) { *p = cvt1(v); }
  static __device__ __forceinline__ void st4(u16* p, float4 v) {
    ushort4 u;
    u.x = cvt1(v.x); u.y = cvt1(v.y); u.z = cvt1(v.z); u.w = cvt1(v.w);
    *(ushort4*)p = u;
  }
};

// broadcast lane `lane`'s value of v to all lanes (v_readlane)
static __device__ __forceinline__ float bcast(float v, int lane) {
  return __uint_as_float(__builtin_amdgcn_readlane(__float_as_uint(v), lane));
}
static __device__ __forceinline__ u32 bcast_u(u32 v, int lane) {
  return (u32)__builtin_amdgcn_readlane((int)v, lane);
}
// bf16-pair unpack; on a uniform (readlane) value these lower to s_lshl/s_and (SALU)
static __device__ __forceinline__ float bflo(u32 u) { return __uint_as_float(u << 16); }
static __device__ __forceinline__ float bfhi(u32 u) { return __uint_as_float(u & 0xffff0000u); }

// ---------------- K0: Z = x + (shift(x) - x) * maa_x ----------------
template <typename ST>
static __global__ __launch_bounds__(256) void k0_z(
    const float* __restrict__ hidden, const float* __restrict__ attn_x,
    const float* __restrict__ maa_x, ST* __restrict__ Z) {
  int idx = blockIdx.x * 256 + threadIdx.x;
  int base = idx * 4;
  int bt = base >> 11;           // / C_
  int c  = base & (C_ - 1);
  int t  = bt & (T_ - 1);
  int b  = bt >> 12;
  float4 x = *(const float4*)(hidden + (size_t)base);
  float4 xp;
  if (t == 0) xp = *(const float4*)(attn_x + (size_t)b * C_ + c);
  else        xp = *(const float4*)(hidden + (size_t)base - C_);
  float4 mx = *(const float4*)(maa_x + c);
  float4 z;
  z.x = x.x + (xp.x - x.x) * mx.x;
  z.y = x.y + (xp.y - x.y) * mx.y;
  z.z = x.z + (xp.z - x.z) * mx.z;
  z.w = x.w + (xp.w - x.w) * mx.w;
  io<ST>::st4(Z + (size_t)base, z);
}

// ---------------- K1: P = tanh(Z @ W1[:, :128]) ----------------
template <typename ST>
static __global__ __launch_bounds__(256) void k1_p(
    const ST* __restrict__ Z, const float* __restrict__ W1,
    float* __restrict__ P) {
  __shared__ float w1s[2][64 * 128];
  int tid = threadIdx.x;
  int lane = tid & 63;
  int wv = tid >> 6;
  int bt0 = blockIdx.x * 16 + wv * 4;
  float acc[4][2];
#pragma unroll
  for (int tk = 0; tk < 4; ++tk) { acc[tk][0] = 0.f; acc[tk][1] = 0.f; }

#pragma unroll
  for (int q = 0; q < 8; ++q) {
    int idx = q * 256 + tid;            // 0..2047
    int cc = idx >> 5;
    int j4 = (idx & 31) * 4;
    *(float4*)&w1s[0][cc * 128 + j4] = *(const float4*)&W1[(size_t)cc * 160 + j4];
  }
  __syncthreads();

#pragma unroll 1
  for (int ch = 0; ch < 32; ++ch) {
    int c0 = ch * 64;
    int buf = ch & 1;
    float z0 = io<ST>::ld(Z + (size_t)(bt0 + 0) * C_ + c0 + lane);
    float z1 = io<ST>::ld(Z + (size_t)(bt0 + 1) * C_ + c0 + lane);
    float z2 = io<ST>::ld(Z + (size_t)(bt0 + 2) * C_ + c0 + lane);
    float z3 = io<ST>::ld(Z + (size_t)(bt0 + 3) * C_ + c0 + lane);
    if (ch + 1 < 32) {
#pragma unroll
      for (int q = 0; q < 8; ++q) {
        int idx = q * 256 + tid;
        int cc = idx >> 5;
        int j4 = (idx & 31) * 4;
        *(float4*)&w1s[buf ^ 1][cc * 128 + j4] =
            *(const float4*)&W1[(size_t)(c0 + 64 + cc) * 160 + j4];
      }
    }
#pragma unroll
    for (int l = 0; l < 64; ++l) {
      float wa = w1s[buf][l * 128 + lane];
      float wb = w1s[buf][l * 128 + lane + 64];
      float s0 = bcast(z0, l), s1 = bcast(z1, l), s2 = bcast(z2, l), s3 = bcast(z3, l);
      acc[0][0] = fmaf(s0, wa, acc[0][0]); acc[0][1] = fmaf(s0, wb, acc[0][1]);
      acc[1][0] = fmaf(s1, wa, acc[1][0]); acc[1][1] = fmaf(s1, wb, acc[1][1]);
      acc[2][0] = fmaf(s2, wa, acc[2][0]); acc[2][1] = fmaf(s2, wb, acc[2][1]);
      acc[3][0] = fmaf(s3, wa, acc[3][0]); acc[3][1] = fmaf(s3, wb, acc[3][1]);
    }
    __syncthreads();
  }
#pragma unroll
  for (int tk = 0; tk < 4; ++tk) {
    P[(size_t)(bt0 + tk) * 128 + lane]      = tanhf(acc[tk][0]);
    P[(size_t)(bt0 + tk) * 128 + lane + 64] = tanhf(acc[tk][1]);
  }
}

// ---------------- K2 (fp32 legacy): four separate outputs ----------------
static __global__ __launch_bounds__(256) void k2_mix_f32(
    const float* __restrict__ hidden, const float* __restrict__ attn_x,
    const float* __restrict__ P, const float* __restrict__ W2,
    const float* __restrict__ maa_w, const float* __restrict__ maa_k,
    const float* __restrict__ maa_v, const float* __restrict__ maa_r,
    float* __restrict__ XW, float* __restrict__ XK,
    float* __restrict__ XV, float* __restrict__ XR) {
  int cb = blockIdx.x & 7;
  int tb = blockIdx.x >> 3;
  int c = cb * 256 + threadIdx.x;
  int bt0 = tb * 16;
  float xv_[16], xx_[16];
#pragma unroll
  for (int tk = 0; tk < 16; ++tk) {
    int bt = bt0 + tk;
    float x = hidden[(size_t)bt * C_ + c];
    int t = bt & (T_ - 1);
    int b = bt >> 12;
    float xp = (t == 0) ? attn_x[(size_t)b * C_ + c]
                        : hidden[(size_t)(bt - 1) * C_ + c];
    xv_[tk] = x;
    xx_[tk] = xp - x;
  }
#pragma unroll
  for (int f = 0; f < 4; ++f) {
    const float* mp = (f == 0) ? maa_w : (f == 1) ? maa_k : (f == 2) ? maa_v : maa_r;
    float* op       = (f == 0) ? XW    : (f == 1) ? XK    : (f == 2) ? XV    : XR;
    float w2r[32];
#pragma unroll
    for (int k = 0; k < 32; ++k) w2r[k] = W2[(size_t)(f * 32 + k) * C_ + c];
    float mf = mp[c];
    for (int tk = 0; tk < 16; ++tk) {
      const float4* p4 = (const float4*)(P + (size_t)(bt0 + tk) * 128 + f * 32);
      float a0 = 0.f, a1 = 0.f, a2 = 0.f, a3 = 0.f;
#pragma unroll
      for (int q = 0; q < 8; ++q) {
        float4 pv = p4[q];
        a0 = fmaf(pv.x, w2r[4 * q + 0], a0);
        a1 = fmaf(pv.y, w2r[4 * q + 1], a1);
        a2 = fmaf(pv.z, w2r[4 * q + 2], a2);
        a3 = fmaf(pv.w, w2r[4 * q + 3], a3);
      }
      float acc = (a0 + a1) + (a2 + a3);
      op[(size_t)(bt0 + tk) * C_ + c] = xv_[tk] + xx_[tk] * (mf + acc);
    }
  }
}

// ---------------- K2 (bf16 packed): XW, XV bf16; RKI = (k<<16)|r per elem ----------------
static __global__ __launch_bounds__(256) void k2_mix_bf16(
    const float* __restrict__ hidden, const float* __restrict__ attn_x,
    const float* __restrict__ P, const float* __restrict__ W2,
    const float* __restrict__ maa_w, const float* __restrict__ maa_k,
    const float* __restrict__ maa_v, const float* __restrict__ maa_r,
    u16* __restrict__ XW, u32* __restrict__ RKI, u16* __restrict__ XV) {
  int cb = blockIdx.x & 7;
  int tb = blockIdx.x >> 3;
  int c = cb * 256 + threadIdx.x;
  int bt0 = tb * 16;
  float xv_[16], xx_[16], xk_[16];
#pragma unroll
  for (int tk = 0; tk < 16; ++tk) {
    int bt = bt0 + tk;
    float x = hidden[(size_t)bt * C_ + c];
    int t = bt & (T_ - 1);
    int b = bt >> 12;
    float xp = (t == 0) ? attn_x[(size_t)b * C_ + c]
                        : hidden[(size_t)(bt - 1) * C_ + c];
    xv_[tk] = x;
    xx_[tk] = xp - x;
  }
#pragma unroll
  for (int f = 0; f < 4; ++f) {
    const float* mp = (f == 0) ? maa_w : (f == 1) ? maa_k : (f == 2) ? maa_v : maa_r;
    float w2r[32];
#pragma unroll
    for (int k = 0; k < 32; ++k) w2r[k] = W2[(size_t)(f * 32 + k) * C_ + c];
    float mf = mp[c];
    for (int tk = 0; tk < 16; ++tk) {
      const float4* p4 = (const float4*)(P + (size_t)(bt0 + tk) * 128 + f * 32);
      float a0 = 0.f, a1 = 0.f, a2 = 0.f, a3 = 0.f;
#pragma unroll
      for (int q = 0; q < 8; ++q) {
        float4 pv = p4[q];
        a0 = fmaf(pv.x, w2r[4 * q + 0], a0);
        a1 = fmaf(pv.y, w2r[4 * q + 1], a1);
        a2 = fmaf(pv.z, w2r[4 * q + 2], a2);
        a3 = fmaf(pv.w, w2r[4 * q + 3], a3);
      }
      float val = xv_[tk] + xx_[tk] * (mf + (a0 + a1) + (a2 + a3));
      size_t off = (size_t)(bt0 + tk) * C_ + c;
      if (f == 0)      io<u16>::st(XW + off, val);
      else if (f == 1) xk_[tk] = val;
      else if (f == 2) io<u16>::st(XV + off, val);
      else {  // f == 3: r -> low half, k -> high half
        u32 pk = (u32)io<u16>::cvt1(val) | ((u32)io<u16>::cvt1(xk_[tk]) << 16);
        RKI[off] = pk;
      }
    }
  }
}

// ---------------- K3: D1 = tanh(XW @ DW1) ----------------
template <typename ST>
static __global__ __launch_bounds__(256) void k3_d1(
    const ST* __restrict__ XW, const float* __restrict__ DW1,
    float* __restrict__ D1) {
  __shared__ float w1s[2][64 * 64];
  int tid = threadIdx.x;
  int lane = tid & 63;
  int wv = tid >> 6;
  int bt0 = blockIdx.x * 16 + wv * 4;
  float acc[4];
#pragma unroll
  for (int tk = 0; tk < 4; ++tk) acc[tk] = 0.f;

#pragma unroll
  for (int q = 0; q < 4; ++q) {
    int idx = q * 256 + tid;            // 0..1023
    int cc = idx >> 4;
    int j4 = (idx & 15) * 4;
    *(float4*)&w1s[0][cc * 64 + j4] = *(const float4*)&DW1[(size_t)cc * 64 + j4];
  }
  __syncthreads();

#pragma unroll 1
  for (int ch = 0; ch < 32; ++ch) {
    int c0 = ch * 64;
    int buf = ch & 1;
    float z0 = io<ST>::ld(XW + (size_t)(bt0 + 0) * C_ + c0 + lane);
    float z1 = io<ST>::ld(XW + (size_t)(bt0 + 1) * C_ + c0 + lane);
    float z2 = io<ST>::ld(XW + (size_t)(bt0 + 2) * C_ + c0 + lane);
    float z3 = io<ST>::ld(XW + (size_t)(bt0 + 3) * C_ + c0 + lane);
    if (ch + 1 < 32) {
#pragma unroll
      for (int q = 0; q < 4; ++q) {
        int idx = q * 256 + tid;
        int cc = idx >> 4;
        int j4 = (idx & 15) * 4;
        *(float4*)&w1s[buf ^ 1][cc * 64 + j4] =
            *(const float4*)&DW1[(size_t)(c0 + 64 + cc) * 64 + j4];
      }
    }
#pragma unroll
    for (int l = 0; l < 64; ++l) {
      float wa = w1s[buf][l * 64 + lane];
      acc[0] = fmaf(bcast(z0, l), wa, acc[0]);
      acc[1] = fmaf(bcast(z1, l), wa, acc[1]);
      acc[2] = fmaf(bcast(z2, l), wa, acc[2]);
      acc[3] = fmaf(bcast(z3, l), wa, acc[3]);
    }
    __syncthreads();
  }
#pragma unroll
  for (int tk = 0; tk < 4; ++tk)
    D1[(size_t)(bt0 + tk) * 64 + lane] = tanhf(acc[tk]);
}

// ---------------- K4: DEC = exp(-exp(time_decay + D1 @ DW2)) ----------------
template <typename ST>
static __global__ __launch_bounds__(256) void k4_decay(
    const float* __restrict__ D1, const float* __restrict__ DW2,
    const float* __restrict__ td, ST* __restrict__ DEC) {
  int cb = blockIdx.x & 7;
  int tb = blockIdx.x >> 3;
  int c = cb * 256 + threadIdx.x;
  int bt0 = tb * 16;
  float w2r[64];
#pragma unroll
  for (int k = 0; k < 64; ++k) w2r[k] = DW2[(size_t)k * C_ + c];
  float tdv = td[c];
  for (int tk = 0; tk < 16; ++tk) {
    const float4* d4 = (const float4*)(D1 + (size_t)(bt0 + tk) * 64);
    float a0 = 0.f, a1 = 0.f, a2 = 0.f, a3 = 0.f;
#pragma unroll
    for (int q = 0; q < 16; ++q) {
      float4 dv = d4[q];
      a0 = fmaf(dv.x, w2r[4 * q + 0], a0);
      a1 = fmaf(dv.y, w2r[4 * q + 1], a1);
      a2 = fmaf(dv.z, w2r[4 * q + 2], a2);
      a3 = fmaf(dv.w, w2r[4 * q + 3], a3);
    }
    float w = tdv + (a0 + a1) + (a2 + a3);
    io<ST>::st(DEC + (size_t)(bt0 + tk) * C_ + c, expf(-expf(w)));
  }
}

// ---------------- K5 (fp32 legacy): round-0 register-broadcast version ----------------
static __global__ __launch_bounds__(256) void k5_intra_f32(
    float* XRQ,
    const float* __restrict__ XK, const float* __restrict__ XV,
    const float* __restrict__ DEC, const float* __restrict__ faaaa,
    float* __restrict__ UC, float* __restrict__ DCp, float* __restrict__ Y) {
  int m = threadIdx.x & 63;
  int chunk = blockIdx.x * 4 + (threadIdx.x >> 6);
  int cc = chunk & (NC_ - 1);
  int h = (chunk >> 6) & (H_ - 1);
  int b = chunk >> 11;
  float u = faaaa[h];
  float s[64];
#pragma unroll
  for (int n = 0; n < 64; ++n) s[n] = 0.f;
  float areg = 1.f;
  size_t row = ((size_t)(b * T_ + cc * L_)) * C_ + h * N_;
  for (int t = 0; t < L_; ++t, row += C_) {
    float vm = XV[row + m];
    float wl = DEC[row + m];
    float kl = XK[row + m];
    float rl = XRQ[row + m];
    float dot = rl * kl;
#pragma unroll
    for (int mk = 32; mk >= 1; mk >>= 1) dot += __shfl_xor(dot, mk, 64);
    float y0 = u * vm * dot, y1 = 0.f, y2 = 0.f, y3 = 0.f;
#pragma unroll
    for (int n = 0; n < 64; n += 4) {
      float rn, kn, wn;
      rn = bcast(rl, n + 0); kn = bcast(kl, n + 0); wn = bcast(wl, n + 0);
      y0 = fmaf(rn, s[n + 0], y0); s[n + 0] = fmaf(wn, s[n + 0], kn * vm);
      rn = bcast(rl, n + 1); kn = bcast(kl, n + 1); wn = bcast(wl, n + 1);
      y1 = fmaf(rn, s[n + 1], y1); s[n + 1] = fmaf(wn, s[n + 1], kn * vm);
      rn = bcast(rl, n + 2); kn = bcast(kl, n + 2); wn = bcast(wl, n + 2);
      y2 = fmaf(rn, s[n + 2], y2); s[n + 2] = fmaf(wn, s[n + 2], kn * vm);
      rn = bcast(rl, n + 3); kn = bcast(kl, n + 3); wn = bcast(wl, n + 3);
      y3 = fmaf(rn, s[n + 3], y3); s[n + 3] = fmaf(wn, s[n + 3], kn * vm);
    }
    XRQ[row + m] = rl * areg;
    areg *= wl;
    Y[row + m] = (y0 + y1) + (y2 + y3);
  }
  size_t ucb = (size_t)chunk * (N_ * N_);
#pragma unroll
  for (int n = 0; n < 64; ++n) UC[ucb + (size_t)n * 64 + m] = s[n];
  DCp[(size_t)chunk * N_ + m] = areg;
}

// ---------------- K5 (bf16 packed): 1.5 readlanes per (t,n) ----------------
// RKI holds (k<<16)|r per element: ONE readlane yields both r_n and k_n; the DEC
// row reinterpreted as u32 yields (w[2i],w[2i+1]) pairs: ONE readlane per two n.
// Unpacks of uniform values lower to s_lshl/s_and on the SALU pipe; every vector
// op consumes at most one SGPR operand (legal), so no extra VALU movs.
// RQ (= r * cumdecay) overwrites the dead XV buffer (v is read per-lane first).
static __global__ __launch_bounds__(256) void k5_intra_bf16(
    const u32* __restrict__ RKI, u16* XVRQ,
    const u16* __restrict__ DEC, const float* __restrict__ faaaa,
    u16* __restrict__ UC, float* __restrict__ DCp, float* __restrict__ Y) {
  int m = threadIdx.x & 63;
  int chunk = blockIdx.x * 4 + (threadIdx.x >> 6);
  int cc = chunk & (NC_ - 1);
  int h = (chunk >> 6) & (H_ - 1);
  int b = chunk >> 11;
  float u = faaaa[h];
  float s[64];
#pragma unroll
  for (int n = 0; n < 64; ++n) s[n] = 0.f;
  float areg = 1.f;
  size_t row = ((size_t)(b * T_ + cc * L_)) * C_ + h * N_;
  for (int t = 0; t < L_; ++t, row += C_) {
    u32 rki = RKI[row + m];                               // (k<<16)|r for c = m
    float vm = io<u16>::ld(XVRQ + row + m);
    float wl = io<u16>::ld(DEC + row + m);
    u32 wpk = ((const u32*)(DEC + row))[m & 31];          // (w[2i],w[2i+1])
    float rl = bflo(rki), kl = bfhi(rki);
    float dot = rl * kl;
#pragma unroll
    for (int mk = 32; mk >= 1; mk >>= 1) dot += __shfl_xor(dot, mk, 64);
    float y0 = u * vm * dot, y1 = 0.f, y2 = 0.f, y3 = 0.f;
#pragma unroll
    for (int i = 0; i < 32; ++i) {
      u32 rk0 = bcast_u(rki, 2 * i);
      u32 rk1 = bcast_u(rki, 2 * i + 1);
      u32 wp  = bcast_u(wpk, i);
      float r0 = bflo(rk0), k0 = bfhi(rk0);
      float r1 = bflo(rk1), k1 = bfhi(rk1);
      float w0 = bflo(wp),  w1 = bfhi(wp);
      int n = 2 * i;
      if (i & 1) {
        y2 = fmaf(r0, s[n], y2);     s[n]     = fmaf(w0, s[n],     k0 * vm);
        y3 = fmaf(r1, s[n + 1], y3); s[n + 1] = fmaf(w1, s[n + 1], k1 * vm);
      } else {
        y0 = fmaf(r0, s[n], y0);     s[n]     = fmaf(w0, s[n],     k0 * vm);
        y1 = fmaf(r1, s[n + 1], y1); s[n + 1] = fmaf(w1, s[n + 1], k1 * vm);
      }
    }
    io<u16>::st(XVRQ + row + m, rl * areg);   // RQ = r * cumdecay (pre-step)
    areg *= wl;
    Y[row + m] = (y0 + y1) + (y2 + y3);
  }
  size_t ucb = (size_t)chunk * (N_ * N_);
#pragma unroll
  for (int n = 0; n < 64; ++n) io<u16>::st(UC + ucb + (size_t)n * 64 + m, s[n]);
  DCp[(size_t)chunk * N_ + m] = areg;
}

// ---------------- K6: inter-chunk state scan ----------------
template <typename ST>
static __global__ __launch_bounds__(256) void k6_scan(
    const float* __restrict__ attn_kv, ST* __restrict__ UC,
    const float* __restrict__ DCp) {
  int msel = blockIdx.x & 3;
  int bh = blockIdx.x >> 2;
  int ml = threadIdx.x & 15;
  int n0 = threadIdx.x >> 4;
  int m = msel * 16 + ml;
  float s[4];
#pragma unroll
  for (int i = 0; i < 4; ++i) {
    int n = n0 + 16 * i;
    s[i] = attn_kv[((size_t)bh * N_ + n) * N_ + m];
  }
  for (int c = 0; c < NC_; ++c) {
    size_t cb = (size_t)bh * NC_ + c;
#pragma unroll
    for (int i = 0; i < 4; ++i) {
      int n = n0 + 16 * i;
      size_t idx = (cb * (size_t)(N_ * N_)) + (size_t)n * 64 + m;
      float uc = io<ST>::ld(UC + idx);
      float dc = DCp[cb * N_ + n];
      io<ST>::st(UC + idx, s[i]);
      s[i] = fmaf(dc, s[i], uc);
    }
  }
}

// ---------------- K7 (fp32 legacy): round-0 version ----------------
static __global__ __launch_bounds__(256) void k7_state_f32(
    const float* __restrict__ RQ, const float* __restrict__ UC,
    float* __restrict__ Y) {
  int m = threadIdx.x & 63;
  int chunk = blockIdx.x * 4 + (threadIdx.x >> 6);
  int cc = chunk & (NC_ - 1);
  int h = (chunk >> 6) & (H_ - 1);
  int b = chunk >> 11;
  float sc[64];
  size_t ucb = (size_t)chunk * (N_ * N_);
#pragma unroll
  for (int n = 0; n < 64; ++n) sc[n] = UC[ucb + (size_t)n * 64 + m];
  size_t row = ((size_t)(b * T_ + cc * L_)) * C_ + h * N_;
  for (int t = 0; t < L_; ++t, row += C_) {
    float ql = RQ[row + m];
    float y0 = Y[row + m], y1 = 0.f, y2 = 0.f, y3 = 0.f;
#pragma unroll
    for (int n = 0; n < 64; n += 4) {
      y0 = fmaf(bcast(ql, n + 0), sc[n + 0], y0);
      y1 = fmaf(bcast(ql, n + 1), sc[n + 1], y1);
      y2 = fmaf(bcast(ql, n + 2), sc[n + 2], y2);
      y3 = fmaf(bcast(ql, n + 3), sc[n + 3], y3);
    }
    Y[row + m] = (y0 + y1) + (y2 + y3);
  }
}

// ---------------- K7 (bf16 packed): 0.5 readlanes per (t,n) ----------------
static __global__ __launch_bounds__(256) void k7_state_bf16(
    const u16* __restrict__ RQ, const u16* __restrict__ UC,
    float* __restrict__ Y) {
  int m = threadIdx.x & 63;
  int chunk = blockIdx.x * 4 + (threadIdx.x >> 6);
  int cc = chunk & (NC_ - 1);
  int h = (chunk >> 6) & (H_ - 1);
  int b = chunk >> 11;
  float sc[64];
  size_t ucb = (size_t)chunk * (N_ * N_);
#pragma unroll
  for (int n = 0; n < 64; ++n) sc[n] = io<u16>::ld(UC + ucb + (size_t)n * 64 + m);
  size_t row = ((size_t)(b * T_ + cc * L_)) * C_ + h * N_;
  for (int t = 0; t < L_; ++t, row += C_) {
    u32 qpk = ((const u32*)(RQ + row))[m & 31];           // (q[2i],q[2i+1])
    float y0 = Y[row + m], y1 = 0.f, y2 = 0.f, y3 = 0.f;
#pragma unroll
    for (int i = 0; i < 32; ++i) {
      u32 qp = bcast_u(qpk, i);
      float q0 = bflo(qp), q1 = bfhi(qp);
      int n = 2 * i;
      if (i & 1) {
        y2 = fmaf(q0, sc[n], y2);
        y3 = fmaf(q1, sc[n + 1], y3);
      } else {
        y0 = fmaf(q0, sc[n], y0);
        y1 = fmaf(q1, sc[n + 1], y1);
      }
    }
    Y[row + m] = (y0 + y1) + (y2 + y3);
  }
}

// ---------------- host ----------------
static void run_f32(void* const* d_in, void* d_out, void* d_ws, hipStream_t stream) {
  const float* hidden = (const float*)d_in[0];
  const float* attn_x = (const float*)d_in[1];
  const float* attn_kv = (const float*)d_in[2];
  const float* maa_x = (const float*)d_in[4];
  const float* maa_w = (const float*)d_in[5];
  const float* maa_k = (const float*)d_in[6];
  const float* maa_v = (const float*)d_in[7];
  const float* maa_r = (const float*)d_in[8];
  const float* W1 = (const float*)d_in[10];
  const float* W2 = (const float*)d_in[11];
  const float* tdec = (const float*)d_in[12];
  const float* DW1 = (const float*)d_in[13];
  const float* DW2 = (const float*)d_in[14];
  const float* faaaa = (const float*)d_in[15];

  const size_t BIG = (size_t)BT_ * C_;
  char* p = (char*)d_ws;
  float* A   = (float*)p; p += BIG * 4;      // Z -> XW -> DEC
  float* XK  = (float*)p; p += BIG * 4;
  float* XV  = (float*)p; p += BIG * 4;
  float* XRQ = (float*)p; p += BIG * 4;      // XR, overwritten by RQ in k5
  float* UC  = (float*)p; p += BIG * 4;
  float* P   = (float*)p; p += (size_t)BT_ * 128 * 4;
  float* D1  = (float*)p; p += (size_t)BT_ * 64 * 4;
  float* DCp = (float*)p;
  float* Y = (float*)d_out;

  k0_z<float>    <<<16384, 256, 0, stream>>>(hidden, attn_x, maa_x, A);
  k1_p<float>    <<<BT_ / 16, 256, 0, stream>>>(A, W1, P);
  k2_mix_f32     <<<(BT_ / 16) * 8, 256, 0, stream>>>(hidden, attn_x, P, W2,
                                                      maa_w, maa_k, maa_v, maa_r,
                                                      A, XK, XV, XRQ);
  k3_d1<float>   <<<BT_ / 16, 256, 0, stream>>>(A, DW1, D1);
  k4_decay<float><<<(BT_ / 16) * 8, 256, 0, stream>>>(D1, DW2, tdec, A);
  k5_intra_f32   <<<B_ * H_ * NC_ / 4, 256, 0, stream>>>(XRQ, XK, XV, A, faaaa,
                                                         UC, DCp, Y);
  k6_scan<float> <<<B_ * H_ * 4, 256, 0, stream>>>(attn_kv, UC, DCp);
  k7_state_f32   <<<B_ * H_ * NC_ / 4, 256, 0, stream>>>(XRQ, UC, Y);
}

static void run_bf16(void* const* d_in, void* d_out, void* d_ws, hipStream_t stream) {
  const float* hidden = (const float*)d_in[0];
  const float* attn_x = (const float*)d_in[1];
  const float* attn_kv = (const float*)d_in[2];
  const float* maa_x = (const float*)d_in[4];
  const float* maa_w = (const float*)d_in[5];
  const float* maa_k = (const float*)d_in[6];
  const float* maa_v = (const float*)d_in[7];
  const float* maa_r = (const float*)d_in[8];
  const float* W1 = (const float*)d_in[10];
  const float* W2 = (const float*)d_in[11];
  const float* tdec = (const float*)d_in[12];
  const float* DW1 = (const float*)d_in[13];
  const float* DW2 = (const float*)d_in[14];
  const float* faaaa = (const float*)d_in[15];

  const size_t BIG = (size_t)BT_ * C_;
  char* p = (char*)d_ws;
  u16* A    = (u16*)p; p += BIG * 2;         // Z -> XW -> DEC
  u32* RKI  = (u32*)p; p += BIG * 4;         // (k<<16)|r packed
  u16* XVRQ = (u16*)p; p += BIG * 2;         // XV, overwritten by RQ in k5
  u16* UC   = (u16*)p; p += BIG * 2;
  float* P   = (float*)p; p += (size_t)BT_ * 128 * 4;
  float* D1  = (float*)p; p += (size_t)BT_ * 64 * 4;
  float* DCp = (float*)p;
  float* Y = (float*)d_out;

  k0_z<u16>    <<<16384, 256, 0, stream>>>(hidden, attn_x, maa_x, A);
  k1_p<u16>    <<<BT_ / 16, 256, 0, stream>>>(A, W1, P);
  k2_mix_bf16  <<<(BT_ / 16) * 8, 256, 0, stream>>>(hidden, attn_x, P, W2,
                                                    maa_w, maa_k, maa_v, maa_r,
                                                    A, RKI, XVRQ);
  k3_d1<u16>   <<<BT_ / 16, 256, 0, stream>>>(A, DW1, D1);
  k4_decay<u16><<<(BT_ / 16) * 8, 256, 0, stream>>>(D1, DW2, tdec, A);
  k5_intra_bf16<<<B_ * H_ * NC_ / 4, 256, 0, stream>>>(RKI, XVRQ, A, faaaa,
                                                       UC, DCp, Y);
  k6_scan<u16> <<<B_ * H_ * 4, 256, 0, stream>>>(attn_kv, UC, DCp);
  k7_state_bf16<<<B_ * H_ * NC_ / 4, 256, 0, stream>>>(XVRQ, UC, Y);
}

extern "C" void kernel_launch(void* const* d_in, const int* in_sizes, int n_in,
                              void* d_out, int out_size, void* d_ws, size_t ws_size,
                              hipStream_t stream) {
  const size_t BIG = (size_t)BT_ * C_;
  const size_t small = (size_t)BT_ * 128 * 4 + (size_t)BT_ * 64 * 4 +
                       (size_t)B_ * H_ * NC_ * N_ * 4;
  const size_t need_f32 = BIG * 4 * 5 + small;   // ~343 MB
  if (ws_size >= need_f32)
    run_f32(d_in, d_out, d_ws, stream);
  else
    run_bf16(d_in, d_out, d_ws, stream);         // bf16 storage + packed RKI, ~175 MB
}

// Round 6
// 848.350 us; speedup vs baseline: 1.1626x; 1.0488x over previous
//
#include <hip/hip_runtime.h>
#include <cmath>

#define B_ 2
#define T_ 4096
#define C_ 2048
#define H_ 32
#define N_ 64
#define L_ 64
#define NC_ 64
#define BT_ 8192

typedef unsigned short u16;
typedef unsigned int u32;
typedef __attribute__((ext_vector_type(8))) short bf16x8;
typedef __attribute__((ext_vector_type(4))) float f32x4;

// ---------- storage abstraction: fp32 or bf16-in-memory (compute fp32) ----------
template <typename T> struct io;
template <> struct io<float> {
  static __device__ __forceinline__ float  ld (const float* p) { return *p; }
  static __device__ __forceinline__ float4 ld4(const float* p) { return *(const float4*)p; }
  static __device__ __forceinline__ void st (float* p, float v) { *p = v; }
  static __device__ __forceinline__ void st4(float* p, float4 v) { *(float4*)p = v; }
};
template <> struct io<u16> {
  static __device__ __forceinline__ float ld(const u16* p) {
    return __uint_as_float((unsigned)(*p) << 16);
  }
  static __device__ __forceinline__ float4 ld4(const u16* p) {
    ushort4 u = *(const ushort4*)p;
    return make_float4(__uint_as_float((unsigned)u.x << 16),
                       __uint_as_float((unsigned)u.y << 16),
                       __uint_as_float((unsigned)u.z << 16),
                       __uint_as_float((unsigned)u.w << 16));
  }
  static __device__ __forceinline__ u16 cvt1(float x) {
    unsigned u = __float_as_uint(x);
    return (u16)((u + 0x7fffu + ((u >> 16) & 1u)) >> 16);
  }
  static __device__ __forceinline__ void st(u16* p, float v) { *p = cvt1(v); }
  static __device__ __forceinline__ void st4(u16* p, float4 v) {
    ushort4 u;
    u.x = cvt1(v.x); u.y = cvt1(v.y); u.z = cvt1(v.z); u.w = cvt1(v.w);
    *(ushort4*)p = u;
  }
};

// broadcast lane `lane`'s value of v to all lanes (v_readlane)
static __device__ __forceinline__ float bcast(float v, int lane) {
  return __uint_as_float(__builtin_amdgcn_readlane(__float_as_uint(v), lane));
}
static __device__ __forceinline__ u32 bcast_u(u32 v, int lane) {
  return (u32)__builtin_amdgcn_readlane((int)v, lane);
}
// bf16-pair unpack; on a uniform (readlane) value these lower to s_lshl/s_and (SALU)
static __device__ __forceinline__ float bflo(u32 u) { return __uint_as_float(u << 16); }
static __device__ __forceinline__ float bfhi(u32 u) { return __uint_as_float(u & 0xffff0000u); }

// ---------------- K0: Z = x + (shift(x) - x) * maa_x ----------------
template <typename ST>
static __global__ __launch_bounds__(256) void k0_z(
    const float* __restrict__ hidden, const float* __restrict__ attn_x,
    const float* __restrict__ maa_x, ST* __restrict__ Z) {
  int idx = blockIdx.x * 256 + threadIdx.x;
  int base = idx * 4;
  int bt = base >> 11;           // / C_
  int c  = base & (C_ - 1);
  int t  = bt & (T_ - 1);
  int b  = bt >> 12;
  float4 x = *(const float4*)(hidden + (size_t)base);
  float4 xp;
  if (t == 0) xp = *(const float4*)(attn_x + (size_t)b * C_ + c);
  else        xp = *(const float4*)(hidden + (size_t)base - C_);
  float4 mx = *(const float4*)(maa_x + c);
  float4 z;
  z.x = x.x + (xp.x - x.x) * mx.x;
  z.y = x.y + (xp.y - x.y) * mx.y;
  z.z = x.z + (xp.z - x.z) * mx.z;
  z.w = x.w + (xp.w - x.w) * mx.w;
  io<ST>::st4(Z + (size_t)base, z);
}

// ---------------- K1: P = tanh(Z @ W1[:, :128]) ----------------
template <typename ST>
static __global__ __launch_bounds__(256) void k1_p(
    const ST* __restrict__ Z, const float* __restrict__ W1,
    float* __restrict__ P) {
  __shared__ float w1s[2][64 * 128];
  int tid = threadIdx.x;
  int lane = tid & 63;
  int wv = tid >> 6;
  int bt0 = blockIdx.x * 16 + wv * 4;
  float acc[4][2];
#pragma unroll
  for (int tk = 0; tk < 4; ++tk) { acc[tk][0] = 0.f; acc[tk][1] = 0.f; }

#pragma unroll
  for (int q = 0; q < 8; ++q) {
    int idx = q * 256 + tid;            // 0..2047
    int cc = idx >> 5;
    int j4 = (idx & 31) * 4;
    *(float4*)&w1s[0][cc * 128 + j4] = *(const float4*)&W1[(size_t)cc * 160 + j4];
  }
  __syncthreads();

#pragma unroll 1
  for (int ch = 0; ch < 32; ++ch) {
    int c0 = ch * 64;
    int buf = ch & 1;
    float z0 = io<ST>::ld(Z + (size_t)(bt0 + 0) * C_ + c0 + lane);
    float z1 = io<ST>::ld(Z + (size_t)(bt0 + 1) * C_ + c0 + lane);
    float z2 = io<ST>::ld(Z + (size_t)(bt0 + 2) * C_ + c0 + lane);
    float z3 = io<ST>::ld(Z + (size_t)(bt0 + 3) * C_ + c0 + lane);
    if (ch + 1 < 32) {
#pragma unroll
      for (int q = 0; q < 8; ++q) {
        int idx = q * 256 + tid;
        int cc = idx >> 5;
        int j4 = (idx & 31) * 4;
        *(float4*)&w1s[buf ^ 1][cc * 128 + j4] =
            *(const float4*)&W1[(size_t)(c0 + 64 + cc) * 160 + j4];
      }
    }
#pragma unroll
    for (int l = 0; l < 64; ++l) {
      float wa = w1s[buf][l * 128 + lane];
      float wb = w1s[buf][l * 128 + lane + 64];
      float s0 = bcast(z0, l), s1 = bcast(z1, l), s2 = bcast(z2, l), s3 = bcast(z3, l);
      acc[0][0] = fmaf(s0, wa, acc[0][0]); acc[0][1] = fmaf(s0, wb, acc[0][1]);
      acc[1][0] = fmaf(s1, wa, acc[1][0]); acc[1][1] = fmaf(s1, wb, acc[1][1]);
      acc[2][0] = fmaf(s2, wa, acc[2][0]); acc[2][1] = fmaf(s2, wb, acc[2][1]);
      acc[3][0] = fmaf(s3, wa, acc[3][0]); acc[3][1] = fmaf(s3, wb, acc[3][1]);
    }
    __syncthreads();
  }
#pragma unroll
  for (int tk = 0; tk < 4; ++tk) {
    P[(size_t)(bt0 + tk) * 128 + lane]      = tanhf(acc[tk][0]);
    P[(size_t)(bt0 + tk) * 128 + lane + 64] = tanhf(acc[tk][1]);
  }
}

// ---------------- K2 (fp32 legacy): four separate outputs ----------------
static __global__ __launch_bounds__(256) void k2_mix_f32(
    const float* __restrict__ hidden, const float* __restrict__ attn_x,
    const float* __restrict__ P, const float* __restrict__ W2,
    const float* __restrict__ maa_w, const float* __restrict__ maa_k,
    const float* __restrict__ maa_v, const float* __restrict__ maa_r,
    float* __restrict__ XW, float* __restrict__ XK,
    float* __restrict__ XV, float* __restrict__ XR) {
  int cb = blockIdx.x & 7;
  int tb = blockIdx.x >> 3;
  int c = cb * 256 + threadIdx.x;
  int bt0 = tb * 16;
  float xv_[16], xx_[16];
#pragma unroll
  for (int tk = 0; tk < 16; ++tk) {
    int bt = bt0 + tk;
    float x = hidden[(size_t)bt * C_ + c];
    int t = bt & (T_ - 1);
    int b = bt >> 12;
    float xp = (t == 0) ? attn_x[(size_t)b * C_ + c]
                        : hidden[(size_t)(bt - 1) * C_ + c];
    xv_[tk] = x;
    xx_[tk] = xp - x;
  }
#pragma unroll
  for (int f = 0; f < 4; ++f) {
    const float* mp = (f == 0) ? maa_w : (f == 1) ? maa_k : (f == 2) ? maa_v : maa_r;
    float* op       = (f == 0) ? XW    : (f == 1) ? XK    : (f == 2) ? XV    : XR;
    float w2r[32];
#pragma unroll
    for (int k = 0; k < 32; ++k) w2r[k] = W2[(size_t)(f * 32 + k) * C_ + c];
    float mf = mp[c];
    for (int tk = 0; tk < 16; ++tk) {
      const float4* p4 = (const float4*)(P + (size_t)(bt0 + tk) * 128 + f * 32);
      float a0 = 0.f, a1 = 0.f, a2 = 0.f, a3 = 0.f;
#pragma unroll
      for (int q = 0; q < 8; ++q) {
        float4 pv = p4[q];
        a0 = fmaf(pv.x, w2r[4 * q + 0], a0);
        a1 = fmaf(pv.y, w2r[4 * q + 1], a1);
        a2 = fmaf(pv.z, w2r[4 * q + 2], a2);
        a3 = fmaf(pv.w, w2r[4 * q + 3], a3);
      }
      float acc = (a0 + a1) + (a2 + a3);
      op[(size_t)(bt0 + tk) * C_ + c] = xv_[tk] + xx_[tk] * (mf + acc);
    }
  }
}

// ---------------- K2 (bf16 packed): XW, XV bf16; RKI = (k<<16)|r per elem ----------------
static __global__ __launch_bounds__(256) void k2_mix_bf16(
    const float* __restrict__ hidden, const float* __restrict__ attn_x,
    const float* __restrict__ P, const float* __restrict__ W2,
    const float* __restrict__ maa_w, const float* __restrict__ maa_k,
    const float* __restrict__ maa_v, const float* __restrict__ maa_r,
    u16* __restrict__ XW, u32* __restrict__ RKI, u16* __restrict__ XV) {
  int cb = blockIdx.x & 7;
  int tb = blockIdx.x >> 3;
  int c = cb * 256 + threadIdx.x;
  int bt0 = tb * 16;
  float xv_[16], xx_[16], xk_[16];
#pragma unroll
  for (int tk = 0; tk < 16; ++tk) {
    int bt = bt0 + tk;
    float x = hidden[(size_t)bt * C_ + c];
    int t = bt & (T_ - 1);
    int b = bt >> 12;
    float xp = (t == 0) ? attn_x[(size_t)b * C_ + c]
                        : hidden[(size_t)(bt - 1) * C_ + c];
    xv_[tk] = x;
    xx_[tk] = xp - x;
  }
#pragma unroll
  for (int f = 0; f < 4; ++f) {
    const float* mp = (f == 0) ? maa_w : (f == 1) ? maa_k : (f == 2) ? maa_v : maa_r;
    float w2r[32];
#pragma unroll
    for (int k = 0; k < 32; ++k) w2r[k] = W2[(size_t)(f * 32 + k) * C_ + c];
    float mf = mp[c];
    for (int tk = 0; tk < 16; ++tk) {
      const float4* p4 = (const float4*)(P + (size_t)(bt0 + tk) * 128 + f * 32);
      float a0 = 0.f, a1 = 0.f, a2 = 0.f, a3 = 0.f;
#pragma unroll
      for (int q = 0; q < 8; ++q) {
        float4 pv = p4[q];
        a0 = fmaf(pv.x, w2r[4 * q + 0], a0);
        a1 = fmaf(pv.y, w2r[4 * q + 1], a1);
        a2 = fmaf(pv.z, w2r[4 * q + 2], a2);
        a3 = fmaf(pv.w, w2r[4 * q + 3], a3);
      }
      float val = xv_[tk] + xx_[tk] * (mf + (a0 + a1) + (a2 + a3));
      size_t off = (size_t)(bt0 + tk) * C_ + c;
      if (f == 0)      io<u16>::st(XW + off, val);
      else if (f == 1) xk_[tk] = val;
      else if (f == 2) io<u16>::st(XV + off, val);
      else {  // f == 3: r -> low half, k -> high half
        u32 pk = (u32)io<u16>::cvt1(val) | ((u32)io<u16>::cvt1(xk_[tk]) << 16);
        RKI[off] = pk;
      }
    }
  }
}

// ---------------- K3: D1 = tanh(XW @ DW1) ----------------
template <typename ST>
static __global__ __launch_bounds__(256) void k3_d1(
    const ST* __restrict__ XW, const float* __restrict__ DW1,
    float* __restrict__ D1) {
  __shared__ float w1s[2][64 * 64];
  int tid = threadIdx.x;
  int lane = tid & 63;
  int wv = tid >> 6;
  int bt0 = blockIdx.x * 16 + wv * 4;
  float acc[4];
#pragma unroll
  for (int tk = 0; tk < 4; ++tk) acc[tk] = 0.f;

#pragma unroll
  for (int q = 0; q < 4; ++q) {
    int idx = q * 256 + tid;            // 0..1023
    int cc = idx >> 4;
    int j4 = (idx & 15) * 4;
    *(float4*)&w1s[0][cc * 64 + j4] = *(const float4*)&DW1[(size_t)cc * 64 + j4];
  }
  __syncthreads();

#pragma unroll 1
  for (int ch = 0; ch < 32; ++ch) {
    int c0 = ch * 64;
    int buf = ch & 1;
    float z0 = io<ST>::ld(XW + (size_t)(bt0 + 0) * C_ + c0 + lane);
    float z1 = io<ST>::ld(XW + (size_t)(bt0 + 1) * C_ + c0 + lane);
    float z2 = io<ST>::ld(XW + (size_t)(bt0 + 2) * C_ + c0 + lane);
    float z3 = io<ST>::ld(XW + (size_t)(bt0 + 3) * C_ + c0 + lane);
    if (ch + 1 < 32) {
#pragma unroll
      for (int q = 0; q < 4; ++q) {
        int idx = q * 256 + tid;
        int cc = idx >> 4;
        int j4 = (idx & 15) * 4;
        *(float4*)&w1s[buf ^ 1][cc * 64 + j4] =
            *(const float4*)&DW1[(size_t)(c0 + 64 + cc) * 64 + j4];
      }
    }
#pragma unroll
    for (int l = 0; l < 64; ++l) {
      float wa = w1s[buf][l * 64 + lane];
      acc[0] = fmaf(bcast(z0, l), wa, acc[0]);
      acc[1] = fmaf(bcast(z1, l), wa, acc[1]);
      acc[2] = fmaf(bcast(z2, l), wa, acc[2]);
      acc[3] = fmaf(bcast(z3, l), wa, acc[3]);
    }
    __syncthreads();
  }
#pragma unroll
  for (int tk = 0; tk < 4; ++tk)
    D1[(size_t)(bt0 + tk) * 64 + lane] = tanhf(acc[tk]);
}

// ---------------- K4: DEC = exp(-exp(time_decay + D1 @ DW2)) ----------------
template <typename ST>
static __global__ __launch_bounds__(256) void k4_decay(
    const float* __restrict__ D1, const float* __restrict__ DW2,
    const float* __restrict__ td, ST* __restrict__ DEC) {
  int cb = blockIdx.x & 7;
  int tb = blockIdx.x >> 3;
  int c = cb * 256 + threadIdx.x;
  int bt0 = tb * 16;
  float w2r[64];
#pragma unroll
  for (int k = 0; k < 64; ++k) w2r[k] = DW2[(size_t)k * C_ + c];
  float tdv = td[c];
  for (int tk = 0; tk < 16; ++tk) {
    const float4* d4 = (const float4*)(D1 + (size_t)(bt0 + tk) * 64);
    float a0 = 0.f, a1 = 0.f, a2 = 0.f, a3 = 0.f;
#pragma unroll
    for (int q = 0; q < 16; ++q) {
      float4 dv = d4[q];
      a0 = fmaf(dv.x, w2r[4 * q + 0], a0);
      a1 = fmaf(dv.y, w2r[4 * q + 1], a1);
      a2 = fmaf(dv.z, w2r[4 * q + 2], a2);
      a3 = fmaf(dv.w, w2r[4 * q + 3], a3);
    }
    float w = tdv + (a0 + a1) + (a2 + a3);
    io<ST>::st(DEC + (size_t)(bt0 + tk) * C_ + c, expf(-expf(w)));
  }
}

// ---------------- K5 (fp32 legacy): round-0 register-broadcast version ----------------
static __global__ __launch_bounds__(256) void k5_intra_f32(
    float* XRQ,
    const float* __restrict__ XK, const float* __restrict__ XV,
    const float* __restrict__ DEC, const float* __restrict__ faaaa,
    float* __restrict__ UC, float* __restrict__ DCp, float* __restrict__ Y) {
  int m = threadIdx.x & 63;
  int chunk = blockIdx.x * 4 + (threadIdx.x >> 6);
  int cc = chunk & (NC_ - 1);
  int h = (chunk >> 6) & (H_ - 1);
  int b = chunk >> 11;
  float u = faaaa[h];
  float s[64];
#pragma unroll
  for (int n = 0; n < 64; ++n) s[n] = 0.f;
  float areg = 1.f;
  size_t row = ((size_t)(b * T_ + cc * L_)) * C_ + h * N_;
  for (int t = 0; t < L_; ++t, row += C_) {
    float vm = XV[row + m];
    float wl = DEC[row + m];
    float kl = XK[row + m];
    float rl = XRQ[row + m];
    float dot = rl * kl;
#pragma unroll
    for (int mk = 32; mk >= 1; mk >>= 1) dot += __shfl_xor(dot, mk, 64);
    float y0 = u * vm * dot, y1 = 0.f, y2 = 0.f, y3 = 0.f;
#pragma unroll
    for (int n = 0; n < 64; n += 4) {
      float rn, kn, wn;
      rn = bcast(rl, n + 0); kn = bcast(kl, n + 0); wn = bcast(wl, n + 0);
      y0 = fmaf(rn, s[n + 0], y0); s[n + 0] = fmaf(wn, s[n + 0], kn * vm);
      rn = bcast(rl, n + 1); kn = bcast(kl, n + 1); wn = bcast(wl, n + 1);
      y1 = fmaf(rn, s[n + 1], y1); s[n + 1] = fmaf(wn, s[n + 1], kn * vm);
      rn = bcast(rl, n + 2); kn = bcast(kl, n + 2); wn = bcast(wl, n + 2);
      y2 = fmaf(rn, s[n + 2], y2); s[n + 2] = fmaf(wn, s[n + 2], kn * vm);
      rn = bcast(rl, n + 3); kn = bcast(kl, n + 3); wn = bcast(wl, n + 3);
      y3 = fmaf(rn, s[n + 3], y3); s[n + 3] = fmaf(wn, s[n + 3], kn * vm);
    }
    XRQ[row + m] = rl * areg;
    areg *= wl;
    Y[row + m] = (y0 + y1) + (y2 + y3);
  }
  size_t ucb = (size_t)chunk * (N_ * N_);
#pragma unroll
  for (int n = 0; n < 64; ++n) UC[ucb + (size_t)n * 64 + m] = s[n];
  DCp[(size_t)chunk * N_ + m] = areg;
}

// ---------------- K5 (bf16 packed + prefetch): 1.5 readlanes per (t,n) ----------------
// Round-4 structure + software pipeline: t+1's four row-loads issue before t's
// inner loop, so the ~500-900 cy global latency hides under the 32-group compute
// instead of stalling in front of it (round-4 PMC: VALUBusy 60%, latency-stalled).
// Prefetch is clamped on the final iteration (re-reads the current row; values
// discarded) so no access ever leaves this chunk's rows — safe by construction.
static __global__ __launch_bounds__(256) void k5_intra_bf16(
    const u32* __restrict__ RKI, u16* XVRQ,
    const u16* __restrict__ DEC, const float* __restrict__ faaaa,
    u16* __restrict__ UC, float* __restrict__ DCp, float* __restrict__ Y) {
  int m = threadIdx.x & 63;
  int chunk = blockIdx.x * 4 + (threadIdx.x >> 6);
  int cc = chunk & (NC_ - 1);
  int h = (chunk >> 6) & (H_ - 1);
  int b = chunk >> 11;
  float u = faaaa[h];
  float s[64];
#pragma unroll
  for (int n = 0; n < 64; ++n) s[n] = 0.f;
  float areg = 1.f;
  size_t row = ((size_t)(b * T_ + cc * L_)) * C_ + h * N_;
  u32 nrki = RKI[row + m];
  float nvm = io<u16>::ld(XVRQ + row + m);
  float nwl = io<u16>::ld(DEC + row + m);
  u32 nwpk = ((const u32*)(DEC + row))[m & 31];
#pragma unroll 1
  for (int t = 0; t < L_; ++t, row += C_) {
    u32 rki = nrki;
    float vm = nvm;
    float wl = nwl;
    u32 wpk = nwpk;
    size_t nx = (t + 1 < L_) ? row + C_ : row;   // clamped prefetch (last iter: dummy)
    nrki = RKI[nx + m];
    nvm = io<u16>::ld(XVRQ + nx + m);
    nwl = io<u16>::ld(DEC + nx + m);
    nwpk = ((const u32*)(DEC + nx))[m & 31];
    float rl = bflo(rki), kl = bfhi(rki);
    float dot = rl * kl;
#pragma unroll
    for (int mk = 32; mk >= 1; mk >>= 1) dot += __shfl_xor(dot, mk, 64);
    float y0 = u * vm * dot, y1 = 0.f, y2 = 0.f, y3 = 0.f;
#pragma unroll
    for (int i = 0; i < 32; ++i) {
      u32 rk0 = bcast_u(rki, 2 * i);
      u32 rk1 = bcast_u(rki, 2 * i + 1);
      u32 wp  = bcast_u(wpk, i);
      float r0 = bflo(rk0), k0 = bfhi(rk0);
      float r1 = bflo(rk1), k1 = bfhi(rk1);
      float w0 = bflo(wp),  w1 = bfhi(wp);
      int n = 2 * i;
      if (i & 1) {
        y2 = fmaf(r0, s[n], y2);     s[n]     = fmaf(w0, s[n],     k0 * vm);
        y3 = fmaf(r1, s[n + 1], y3); s[n + 1] = fmaf(w1, s[n + 1], k1 * vm);
      } else {
        y0 = fmaf(r0, s[n], y0);     s[n]     = fmaf(w0, s[n],     k0 * vm);
        y1 = fmaf(r1, s[n + 1], y1); s[n + 1] = fmaf(w1, s[n + 1], k1 * vm);
      }
    }
    io<u16>::st(XVRQ + row + m, rl * areg);   // RQ = r * cumdecay (pre-step)
    areg *= wl;
    Y[row + m] = (y0 + y1) + (y2 + y3);
  }
  size_t ucb = (size_t)chunk * (N_ * N_);
#pragma unroll
  for (int n = 0; n < 64; ++n) io<u16>::st(UC + ucb + (size_t)n * 64 + m, s[n]);
  DCp[(size_t)chunk * N_ + m] = areg;
}

// ---------------- K6: inter-chunk state scan ----------------
template <typename ST>
static __global__ __launch_bounds__(256) void k6_scan(
    const float* __restrict__ attn_kv, ST* __restrict__ UC,
    const float* __restrict__ DCp) {
  int msel = blockIdx.x & 3;
  int bh = blockIdx.x >> 2;
  int ml = threadIdx.x & 15;
  int n0 = threadIdx.x >> 4;
  int m = msel * 16 + ml;
  float s[4];
#pragma unroll
  for (int i = 0; i < 4; ++i) {
    int n = n0 + 16 * i;
    s[i] = attn_kv[((size_t)bh * N_ + n) * N_ + m];
  }
  for (int c = 0; c < NC_; ++c) {
    size_t cb = (size_t)bh * NC_ + c;
#pragma unroll
    for (int i = 0; i < 4; ++i) {
      int n = n0 + 16 * i;
      size_t idx = (cb * (size_t)(N_ * N_)) + (size_t)n * 64 + m;
      float uc = io<ST>::ld(UC + idx);
      float dc = DCp[cb * N_ + n];
      io<ST>::st(UC + idx, s[i]);
      s[i] = fmaf(dc, s[i], uc);
    }
  }
}

// ---------------- K7 (fp32 legacy): round-0 version ----------------
static __global__ __launch_bounds__(256) void k7_state_f32(
    const float* __restrict__ RQ, const float* __restrict__ UC,
    float* __restrict__ Y) {
  int m = threadIdx.x & 63;
  int chunk = blockIdx.x * 4 + (threadIdx.x >> 6);
  int cc = chunk & (NC_ - 1);
  int h = (chunk >> 6) & (H_ - 1);
  int b = chunk >> 11;
  float sc[64];
  size_t ucb = (size_t)chunk * (N_ * N_);
#pragma unroll
  for (int n = 0; n < 64; ++n) sc[n] = UC[ucb + (size_t)n * 64 + m];
  size_t row = ((size_t)(b * T_ + cc * L_)) * C_ + h * N_;
  for (int t = 0; t < L_; ++t, row += C_) {
    float ql = RQ[row + m];
    float y0 = Y[row + m], y1 = 0.f, y2 = 0.f, y3 = 0.f;
#pragma unroll
    for (int n = 0; n < 64; n += 4) {
      y0 = fmaf(bcast(ql, n + 0), sc[n + 0], y0);
      y1 = fmaf(bcast(ql, n + 1), sc[n + 1], y1);
      y2 = fmaf(bcast(ql, n + 2), sc[n + 2], y2);
      y3 = fmaf(bcast(ql, n + 3), sc[n + 3], y3);
    }
    Y[row + m] = (y0 + y1) + (y2 + y3);
  }
}

// ---------------- K7 (bf16, MFMA): Y += RQ(64x64) @ S0(64x64) per chunk ----------------
// One block per chunk. S0 staged transposed + XOR-swizzled into LDS (8 KB) so
// B-fragments are contiguous 16B ds_read_b128. 4 waves x 4 col-tiles x 2 k-steps of
// mfma_f32_16x16x32_bf16. A: lane holds RQ[t0+(lane&15)][kg*8 ..+8] (contiguous 16B
// global load). C/D layout (guide-verified): col=lane&15, row=(lane>>4)*4+reg.
static __global__ __launch_bounds__(256) void k7_mfma(
    const u16* __restrict__ RQ, const u16* __restrict__ UC,
    float* __restrict__ Y) {
  __shared__ u16 st[64][64];   // st[m][n ^ ((m&7)<<3)] = S0[n][m]
  int tid = threadIdx.x;
  int chunk = blockIdx.x;
  int cc = chunk & (NC_ - 1);
  int h = (chunk >> 6) & (H_ - 1);
  int b = chunk >> 11;
  const u16* S0 = UC + (size_t)chunk * (N_ * N_);
  {
    int n = tid >> 2;               // 0..63
    int m0 = (tid & 3) << 4;        // 0,16,32,48
#pragma unroll
    for (int j = 0; j < 16; ++j) {
      int m = m0 + j;
      st[m][n ^ ((m & 7) << 3)] = S0[n * 64 + m];
    }
  }
  __syncthreads();
  int lane = tid & 63;
  int wv = tid >> 6;
  int trow = lane & 15;
  int kg = lane >> 4;
  int t0 = wv << 4;
  size_t arow = ((size_t)(b * T_ + cc * L_ + t0 + trow)) * C_ + h * N_;
  bf16x8 a0 = *(const bf16x8*)(RQ + arow + kg * 8);        // k = 0..31 slice
  bf16x8 a1 = *(const bf16x8*)(RQ + arow + 32 + kg * 8);   // k = 32..63 slice
#pragma unroll
  for (int ct = 0; ct < 4; ++ct) {
    int col = ct * 16 + trow;
    int sw = (col & 7) << 3;
    bf16x8 b0 = *(const bf16x8*)&st[col][(kg * 8) ^ sw];
    bf16x8 b1 = *(const bf16x8*)&st[col][(32 + kg * 8) ^ sw];
    f32x4 c = {0.f, 0.f, 0.f, 0.f};
    c = __builtin_amdgcn_mfma_f32_16x16x32_bf16(a0, b0, c, 0, 0, 0);
    c = __builtin_amdgcn_mfma_f32_16x16x32_bf16(a1, b1, c, 0, 0, 0);
    size_t ybase = ((size_t)(b * T_ + cc * L_ + t0 + kg * 4)) * C_ + h * N_ + ct * 16 + trow;
#pragma unroll
    for (int rg = 0; rg < 4; ++rg)
      Y[ybase + (size_t)rg * C_] += c[rg];
  }
}

// ---------------- host ----------------
static void run_f32(void* const* d_in, void* d_out, void* d_ws, hipStream_t stream) {
  const float* hidden = (const float*)d_in[0];
  const float* attn_x = (const float*)d_in[1];
  const float* attn_kv = (const float*)d_in[2];
  const float* maa_x = (const float*)d_in[4];
  const float* maa_w = (const float*)d_in[5];
  const float* maa_k = (const float*)d_in[6];
  const float* maa_v = (const float*)d_in[7];
  const float* maa_r = (const float*)d_in[8];
  const float* W1 = (const float*)d_in[10];
  const float* W2 = (const float*)d_in[11];
  const float* tdec = (const float*)d_in[12];
  const float* DW1 = (const float*)d_in[13];
  const float* DW2 = (const float*)d_in[14];
  const float* faaaa = (const float*)d_in[15];

  const size_t BIG = (size_t)BT_ * C_;
  char* p = (char*)d_ws;
  float* A   = (float*)p; p += BIG * 4;      // Z -> XW -> DEC
  float* XK  = (float*)p; p += BIG * 4;
  float* XV  = (float*)p; p += BIG * 4;
  float* XRQ = (float*)p; p += BIG * 4;      // XR, overwritten by RQ in k5
  float* UC  = (float*)p; p += BIG * 4;
  float* P   = (float*)p; p += (size_t)BT_ * 128 * 4;
  float* D1  = (float*)p; p += (size_t)BT_ * 64 * 4;
  float* DCp = (float*)p;
  float* Y = (float*)d_out;

  k0_z<float>    <<<16384, 256, 0, stream>>>(hidden, attn_x, maa_x, A);
  k1_p<float>    <<<BT_ / 16, 256, 0, stream>>>(A, W1, P);
  k2_mix_f32     <<<(BT_ / 16) * 8, 256, 0, stream>>>(hidden, attn_x, P, W2,
                                                      maa_w, maa_k, maa_v, maa_r,
                                                      A, XK, XV, XRQ);
  k3_d1<float>   <<<BT_ / 16, 256, 0, stream>>>(A, DW1, D1);
  k4_decay<float><<<(BT_ / 16) * 8, 256, 0, stream>>>(D1, DW2, tdec, A);
  k5_intra_f32   <<<B_ * H_ * NC_ / 4, 256, 0, stream>>>(XRQ, XK, XV, A, faaaa,
                                                         UC, DCp, Y);
  k6_scan<float> <<<B_ * H_ * 4, 256, 0, stream>>>(attn_kv, UC, DCp);
  k7_state_f32   <<<B_ * H_ * NC_ / 4, 256, 0, stream>>>(XRQ, UC, Y);
}

static void run_bf16(void* const* d_in, void* d_out, void* d_ws, hipStream_t stream) {
  const float* hidden = (const float*)d_in[0];
  const float* attn_x = (const float*)d_in[1];
  const float* attn_kv = (const float*)d_in[2];
  const float* maa_x = (const float*)d_in[4];
  const float* maa_w = (const float*)d_in[5];
  const float* maa_k = (const float*)d_in[6];
  const float* maa_v = (const float*)d_in[7];
  const float* maa_r = (const float*)d_in[8];
  const float* W1 = (const float*)d_in[10];
  const float* W2 = (const float*)d_in[11];
  const float* tdec = (const float*)d_in[12];
  const float* DW1 = (const float*)d_in[13];
  const float* DW2 = (const float*)d_in[14];
  const float* faaaa = (const float*)d_in[15];

  const size_t BIG = (size_t)BT_ * C_;
  char* p = (char*)d_ws;
  u16* A    = (u16*)p; p += BIG * 2;         // Z -> XW -> DEC
  u32* RKI  = (u32*)p; p += BIG * 4;         // (k<<16)|r packed
  u16* XVRQ = (u16*)p; p += BIG * 2;         // XV, overwritten by RQ in k5
  u16* UC   = (u16*)p; p += BIG * 2;
  float* P   = (float*)p; p += (size_t)BT_ * 128 * 4;
  float* D1  = (float*)p; p += (size_t)BT_ * 64 * 4;
  float* DCp = (float*)p;
  float* Y = (float*)d_out;

  k0_z<u16>    <<<16384, 256, 0, stream>>>(hidden, attn_x, maa_x, A);
  k1_p<u16>    <<<BT_ / 16, 256, 0, stream>>>(A, W1, P);
  k2_mix_bf16  <<<(BT_ / 16) * 8, 256, 0, stream>>>(hidden, attn_x, P, W2,
                                                    maa_w, maa_k, maa_v, maa_r,
                                                    A, RKI, XVRQ);
  k3_d1<u16>   <<<BT_ / 16, 256, 0, stream>>>(A, DW1, D1);
  k4_decay<u16><<<(BT_ / 16) * 8, 256, 0, stream>>>(D1, DW2, tdec, A);
  k5_intra_bf16<<<B_ * H_ * NC_ / 4, 256, 0, stream>>>(RKI, XVRQ, A, faaaa,
                                                       UC, DCp, Y);
  k6_scan<u16> <<<B_ * H_ * 4, 256, 0, stream>>>(attn_kv, UC, DCp);
  k7_mfma      <<<B_ * H_ * NC_, 256, 0, stream>>>(XVRQ, UC, Y);
}

extern "C" void kernel_launch(void* const* d_in, const int* in_sizes, int n_in,
                              void* d_out, int out_size, void* d_ws, size_t ws_size,
                              hipStream_t stream) {
  const size_t BIG = (size_t)BT_ * C_;
  const size_t small = (size_t)BT_ * 128 * 4 + (size_t)BT_ * 64 * 4 +
                       (size_t)B_ * H_ * NC_ * N_ * 4;
  const size_t need_f32 = BIG * 4 * 5 + small;   // ~343 MB
  if (ws_size >= need_f32)
    run_f32(d_in, d_out, d_ws, stream);
  else
    run_bf16(d_in, d_out, d_ws, stream);         // bf16 storage + packed RKI, ~175 MB
}

// Round 7
// 745.743 us; speedup vs baseline: 1.3225x; 1.1376x over previous
//
#include <hip/hip_runtime.h>
#include <cmath>

#define B_ 2
#define T_ 4096
#define C_ 2048
#define H_ 32
#define N_ 64
#define L_ 64
#define NC_ 64
#define BT_ 8192

typedef unsigned short u16;
typedef unsigned int u32;
typedef __attribute__((ext_vector_type(8))) short bf16x8;
typedef __attribute__((ext_vector_type(4))) float f32x4;

// ---------- storage abstraction: fp32 or bf16-in-memory (compute fp32) ----------
template <typename T> struct io;
template <> struct io<float> {
  static __device__ __forceinline__ float  ld (const float* p) { return *p; }
  static __device__ __forceinline__ float4 ld4(const float* p) { return *(const float4*)p; }
  static __device__ __forceinline__ void st (float* p, float v) { *p = v; }
  static __device__ __forceinline__ void st4(float* p, float4 v) { *(float4*)p = v; }
};
template <> struct io<u16> {
  static __device__ __forceinline__ float ld(const u16* p) {
    return __uint_as_float((unsigned)(*p) << 16);
  }
  static __device__ __forceinline__ float4 ld4(const u16* p) {
    ushort4 u = *(const ushort4*)p;
    return make_float4(__uint_as_float((unsigned)u.x << 16),
                       __uint_as_float((unsigned)u.y << 16),
                       __uint_as_float((unsigned)u.z << 16),
                       __uint_as_float((unsigned)u.w << 16));
  }
  static __device__ __forceinline__ u16 cvt1(float x) {
    unsigned u = __float_as_uint(x);
    return (u16)((u + 0x7fffu + ((u >> 16) & 1u)) >> 16);
  }
  static __device__ __forceinline__ void st(u16* p, float v) { *p = cvt1(v); }
  static __device__ __forceinline__ void st4(u16* p, float4 v) {
    ushort4 u;
    u.x = cvt1(v.x); u.y = cvt1(v.y); u.z = cvt1(v.z); u.w = cvt1(v.w);
    *(ushort4*)p = u;
  }
};

// broadcast lane `lane`'s value of v to all lanes (v_readlane)
static __device__ __forceinline__ float bcast(float v, int lane) {
  return __uint_as_float(__builtin_amdgcn_readlane(__float_as_uint(v), lane));
}
static __device__ __forceinline__ u32 bcast_u(u32 v, int lane) {
  return (u32)__builtin_amdgcn_readlane((int)v, lane);
}
// bf16-pair unpack; on a uniform (readlane) value these lower to s_lshl/s_and (SALU)
static __device__ __forceinline__ float bflo(u32 u) { return __uint_as_float(u << 16); }
static __device__ __forceinline__ float bfhi(u32 u) { return __uint_as_float(u & 0xffff0000u); }

// ---------------- K0: Z = x + (shift(x) - x) * maa_x ----------------
template <typename ST>
static __global__ __launch_bounds__(256) void k0_z(
    const float* __restrict__ hidden, const float* __restrict__ attn_x,
    const float* __restrict__ maa_x, ST* __restrict__ Z) {
  int idx = blockIdx.x * 256 + threadIdx.x;
  int base = idx * 4;
  int bt = base >> 11;           // / C_
  int c  = base & (C_ - 1);
  int t  = bt & (T_ - 1);
  int b  = bt >> 12;
  float4 x = *(const float4*)(hidden + (size_t)base);
  float4 xp;
  if (t == 0) xp = *(const float4*)(attn_x + (size_t)b * C_ + c);
  else        xp = *(const float4*)(hidden + (size_t)base - C_);
  float4 mx = *(const float4*)(maa_x + c);
  float4 z;
  z.x = x.x + (xp.x - x.x) * mx.x;
  z.y = x.y + (xp.y - x.y) * mx.y;
  z.z = x.z + (xp.z - x.z) * mx.z;
  z.w = x.w + (xp.w - x.w) * mx.w;
  io<ST>::st4(Z + (size_t)base, z);
}

// ---------------- WT: transpose+convert weights to bf16 ----------------
// W1 [2048][160] f32 -> W1T [128][2048] bf16 ; DW1 [2048][64] f32 -> DW1T [64][2048] bf16
// Blocks 0..63: W1 (32 c-tiles x 2 j-tiles); 64..95: DW1 (32 c-tiles).
static __global__ __launch_bounds__(256) void wt_prep(
    const float* __restrict__ W1, const float* __restrict__ DW1,
    u16* __restrict__ W1T, u16* __restrict__ DW1T) {
  __shared__ u16 tile[64][65];
  int blk = blockIdx.x;
  const float* src; u16* dst; int c0, j0, srcld;
  if (blk < 64) { src = W1;  dst = W1T;  c0 = (blk >> 1) * 64; j0 = (blk & 1) * 64; srcld = 160; }
  else          { src = DW1; dst = DW1T; c0 = (blk - 64) * 64; j0 = 0;              srcld = 64;  }
  int tid = threadIdx.x;
  int jj = tid & 63, cr = tid >> 6;
#pragma unroll
  for (int i = 0; i < 16; ++i) {
    int c = cr + i * 4;
    tile[c][jj] = io<u16>::cvt1(src[(size_t)(c0 + c) * srcld + j0 + jj]);
  }
  __syncthreads();
  int cw = tid & 63, jr = tid >> 6;
#pragma unroll
  for (int i = 0; i < 16; ++i) {
    int j = jr + i * 4;
    dst[(size_t)(j0 + j) * 2048 + c0 + cw] = tile[cw][j];
  }
}

// ---------------- K1 (bf16, MFMA): P = tanh(Z @ W1) ----------------
// A: Z rows from global (row = lane&15, k-slice (lane>>4)*8) — k7-validated pattern.
// B: W1T[j][c] rows from global (col = lane&15, same k-slice).
// Block: 16 bt x 128 j; 4 waves x 2 j-tiles. No LDS, no barriers.
static __global__ __launch_bounds__(256) void k1_mfma(
    const u16* __restrict__ Z, const u16* __restrict__ W1T,
    float* __restrict__ P) {
  int tid = threadIdx.x;
  int lane = tid & 63, wv = tid >> 6;
  int bt0 = blockIdx.x * 16;
  int j0 = wv * 32;
  int row = lane & 15, kg = lane >> 4;
  const u16* za  = Z   + (size_t)(bt0 + row) * C_ + kg * 8;
  const u16* b0p = W1T + (size_t)(j0 + row) * C_ + kg * 8;
  const u16* b1p = W1T + (size_t)(j0 + 16 + row) * C_ + kg * 8;
  f32x4 acc0 = {0.f, 0.f, 0.f, 0.f}, acc1 = {0.f, 0.f, 0.f, 0.f};
#pragma unroll 8
  for (int c0 = 0; c0 < C_; c0 += 32) {
    bf16x8 a  = *(const bf16x8*)(za + c0);
    bf16x8 b0 = *(const bf16x8*)(b0p + c0);
    bf16x8 b1 = *(const bf16x8*)(b1p + c0);
    acc0 = __builtin_amdgcn_mfma_f32_16x16x32_bf16(a, b0, acc0, 0, 0, 0);
    acc1 = __builtin_amdgcn_mfma_f32_16x16x32_bf16(a, b1, acc1, 0, 0, 0);
  }
  int orow = bt0 + kg * 4;
  int ocol = row;
#pragma unroll
  for (int rg = 0; rg < 4; ++rg) {
    P[(size_t)(orow + rg) * 128 + j0 + ocol]      = tanhf(acc0[rg]);
    P[(size_t)(orow + rg) * 128 + j0 + 16 + ocol] = tanhf(acc1[rg]);
  }
}

// ---------------- K1 (fp32 legacy): readlane-broadcast GEMM ----------------
template <typename ST>
static __global__ __launch_bounds__(256) void k1_p(
    const ST* __restrict__ Z, const float* __restrict__ W1,
    float* __restrict__ P) {
  __shared__ float w1s[2][64 * 128];
  int tid = threadIdx.x;
  int lane = tid & 63;
  int wv = tid >> 6;
  int bt0 = blockIdx.x * 16 + wv * 4;
  float acc[4][2];
#pragma unroll
  for (int tk = 0; tk < 4; ++tk) { acc[tk][0] = 0.f; acc[tk][1] = 0.f; }

#pragma unroll
  for (int q = 0; q < 8; ++q) {
    int idx = q * 256 + tid;
    int cc = idx >> 5;
    int j4 = (idx & 31) * 4;
    *(float4*)&w1s[0][cc * 128 + j4] = *(const float4*)&W1[(size_t)cc * 160 + j4];
  }
  __syncthreads();

#pragma unroll 1
  for (int ch = 0; ch < 32; ++ch) {
    int c0 = ch * 64;
    int buf = ch & 1;
    float z0 = io<ST>::ld(Z + (size_t)(bt0 + 0) * C_ + c0 + lane);
    float z1 = io<ST>::ld(Z + (size_t)(bt0 + 1) * C_ + c0 + lane);
    float z2 = io<ST>::ld(Z + (size_t)(bt0 + 2) * C_ + c0 + lane);
    float z3 = io<ST>::ld(Z + (size_t)(bt0 + 3) * C_ + c0 + lane);
    if (ch + 1 < 32) {
#pragma unroll
      for (int q = 0; q < 8; ++q) {
        int idx = q * 256 + tid;
        int cc = idx >> 5;
        int j4 = (idx & 31) * 4;
        *(float4*)&w1s[buf ^ 1][cc * 128 + j4] =
            *(const float4*)&W1[(size_t)(c0 + 64 + cc) * 160 + j4];
      }
    }
#pragma unroll
    for (int l = 0; l < 64; ++l) {
      float wa = w1s[buf][l * 128 + lane];
      float wb = w1s[buf][l * 128 + lane + 64];
      float s0 = bcast(z0, l), s1 = bcast(z1, l), s2 = bcast(z2, l), s3 = bcast(z3, l);
      acc[0][0] = fmaf(s0, wa, acc[0][0]); acc[0][1] = fmaf(s0, wb, acc[0][1]);
      acc[1][0] = fmaf(s1, wa, acc[1][0]); acc[1][1] = fmaf(s1, wb, acc[1][1]);
      acc[2][0] = fmaf(s2, wa, acc[2][0]); acc[2][1] = fmaf(s2, wb, acc[2][1]);
      acc[3][0] = fmaf(s3, wa, acc[3][0]); acc[3][1] = fmaf(s3, wb, acc[3][1]);
    }
    __syncthreads();
  }
#pragma unroll
  for (int tk = 0; tk < 4; ++tk) {
    P[(size_t)(bt0 + tk) * 128 + lane]      = tanhf(acc[tk][0]);
    P[(size_t)(bt0 + tk) * 128 + lane + 64] = tanhf(acc[tk][1]);
  }
}

// ---------------- K2 (fp32 legacy): four separate outputs ----------------
static __global__ __launch_bounds__(256) void k2_mix_f32(
    const float* __restrict__ hidden, const float* __restrict__ attn_x,
    const float* __restrict__ P, const float* __restrict__ W2,
    const float* __restrict__ maa_w, const float* __restrict__ maa_k,
    const float* __restrict__ maa_v, const float* __restrict__ maa_r,
    float* __restrict__ XW, float* __restrict__ XK,
    float* __restrict__ XV, float* __restrict__ XR) {
  int cb = blockIdx.x & 7;
  int tb = blockIdx.x >> 3;
  int c = cb * 256 + threadIdx.x;
  int bt0 = tb * 16;
  float xv_[16], xx_[16];
#pragma unroll
  for (int tk = 0; tk < 16; ++tk) {
    int bt = bt0 + tk;
    float x = hidden[(size_t)bt * C_ + c];
    int t = bt & (T_ - 1);
    int b = bt >> 12;
    float xp = (t == 0) ? attn_x[(size_t)b * C_ + c]
                        : hidden[(size_t)(bt - 1) * C_ + c];
    xv_[tk] = x;
    xx_[tk] = xp - x;
  }
#pragma unroll
  for (int f = 0; f < 4; ++f) {
    const float* mp = (f == 0) ? maa_w : (f == 1) ? maa_k : (f == 2) ? maa_v : maa_r;
    float* op       = (f == 0) ? XW    : (f == 1) ? XK    : (f == 2) ? XV    : XR;
    float w2r[32];
#pragma unroll
    for (int k = 0; k < 32; ++k) w2r[k] = W2[(size_t)(f * 32 + k) * C_ + c];
    float mf = mp[c];
    for (int tk = 0; tk < 16; ++tk) {
      const float4* p4 = (const float4*)(P + (size_t)(bt0 + tk) * 128 + f * 32);
      float a0 = 0.f, a1 = 0.f, a2 = 0.f, a3 = 0.f;
#pragma unroll
      for (int q = 0; q < 8; ++q) {
        float4 pv = p4[q];
        a0 = fmaf(pv.x, w2r[4 * q + 0], a0);
        a1 = fmaf(pv.y, w2r[4 * q + 1], a1);
        a2 = fmaf(pv.z, w2r[4 * q + 2], a2);
        a3 = fmaf(pv.w, w2r[4 * q + 3], a3);
      }
      float acc = (a0 + a1) + (a2 + a3);
      op[(size_t)(bt0 + tk) * C_ + c] = xv_[tk] + xx_[tk] * (mf + acc);
    }
  }
}

// ---------------- K2 (bf16 packed): XW, XV bf16; RKI = (k<<16)|r per elem ----------------
static __global__ __launch_bounds__(256) void k2_mix_bf16(
    const float* __restrict__ hidden, const float* __restrict__ attn_x,
    const float* __restrict__ P, const float* __restrict__ W2,
    const float* __restrict__ maa_w, const float* __restrict__ maa_k,
    const float* __restrict__ maa_v, const float* __restrict__ maa_r,
    u16* __restrict__ XW, u32* __restrict__ RKI, u16* __restrict__ XV) {
  int cb = blockIdx.x & 7;
  int tb = blockIdx.x >> 3;
  int c = cb * 256 + threadIdx.x;
  int bt0 = tb * 16;
  float xv_[16], xx_[16], xk_[16];
#pragma unroll
  for (int tk = 0; tk < 16; ++tk) {
    int bt = bt0 + tk;
    float x = hidden[(size_t)bt * C_ + c];
    int t = bt & (T_ - 1);
    int b = bt >> 12;
    float xp = (t == 0) ? attn_x[(size_t)b * C_ + c]
                        : hidden[(size_t)(bt - 1) * C_ + c];
    xv_[tk] = x;
    xx_[tk] = xp - x;
  }
#pragma unroll
  for (int f = 0; f < 4; ++f) {
    const float* mp = (f == 0) ? maa_w : (f == 1) ? maa_k : (f == 2) ? maa_v : maa_r;
    float w2r[32];
#pragma unroll
    for (int k = 0; k < 32; ++k) w2r[k] = W2[(size_t)(f * 32 + k) * C_ + c];
    float mf = mp[c];
    for (int tk = 0; tk < 16; ++tk) {
      const float4* p4 = (const float4*)(P + (size_t)(bt0 + tk) * 128 + f * 32);
      float a0 = 0.f, a1 = 0.f, a2 = 0.f, a3 = 0.f;
#pragma unroll
      for (int q = 0; q < 8; ++q) {
        float4 pv = p4[q];
        a0 = fmaf(pv.x, w2r[4 * q + 0], a0);
        a1 = fmaf(pv.y, w2r[4 * q + 1], a1);
        a2 = fmaf(pv.z, w2r[4 * q + 2], a2);
        a3 = fmaf(pv.w, w2r[4 * q + 3], a3);
      }
      float val = xv_[tk] + xx_[tk] * (mf + (a0 + a1) + (a2 + a3));
      size_t off = (size_t)(bt0 + tk) * C_ + c;
      if (f == 0)      io<u16>::st(XW + off, val);
      else if (f == 1) xk_[tk] = val;
      else if (f == 2) io<u16>::st(XV + off, val);
      else {  // f == 3: r -> low half, k -> high half
        u32 pk = (u32)io<u16>::cvt1(val) | ((u32)io<u16>::cvt1(xk_[tk]) << 16);
        RKI[off] = pk;
      }
    }
  }
}

// ---------------- K3 (bf16, MFMA): D1 = tanh(XW @ DW1) ----------------
// Same validated fragment pattern as k1_mfma; 4 waves x 1 j-tile (j = 64).
static __global__ __launch_bounds__(256) void k3_mfma(
    const u16* __restrict__ XW, const u16* __restrict__ DW1T,
    float* __restrict__ D1) {
  int tid = threadIdx.x;
  int lane = tid & 63, wv = tid >> 6;
  int bt0 = blockIdx.x * 16;
  int j0 = wv * 16;
  int row = lane & 15, kg = lane >> 4;
  const u16* xa = XW   + (size_t)(bt0 + row) * C_ + kg * 8;
  const u16* bp = DW1T + (size_t)(j0 + row) * C_ + kg * 8;
  f32x4 acc = {0.f, 0.f, 0.f, 0.f};
#pragma unroll 8
  for (int c0 = 0; c0 < C_; c0 += 32) {
    bf16x8 a = *(const bf16x8*)(xa + c0);
    bf16x8 b = *(const bf16x8*)(bp + c0);
    acc = __builtin_amdgcn_mfma_f32_16x16x32_bf16(a, b, acc, 0, 0, 0);
  }
  int orow = bt0 + kg * 4;
#pragma unroll
  for (int rg = 0; rg < 4; ++rg)
    D1[(size_t)(orow + rg) * 64 + j0 + row] = tanhf(acc[rg]);
}

// ---------------- K3 (fp32 legacy) ----------------
template <typename ST>
static __global__ __launch_bounds__(256) void k3_d1(
    const ST* __restrict__ XW, const float* __restrict__ DW1,
    float* __restrict__ D1) {
  __shared__ float w1s[2][64 * 64];
  int tid = threadIdx.x;
  int lane = tid & 63;
  int wv = tid >> 6;
  int bt0 = blockIdx.x * 16 + wv * 4;
  float acc[4];
#pragma unroll
  for (int tk = 0; tk < 4; ++tk) acc[tk] = 0.f;

#pragma unroll
  for (int q = 0; q < 4; ++q) {
    int idx = q * 256 + tid;
    int cc = idx >> 4;
    int j4 = (idx & 15) * 4;
    *(float4*)&w1s[0][cc * 64 + j4] = *(const float4*)&DW1[(size_t)cc * 64 + j4];
  }
  __syncthreads();

#pragma unroll 1
  for (int ch = 0; ch < 32; ++ch) {
    int c0 = ch * 64;
    int buf = ch & 1;
    float z0 = io<ST>::ld(XW + (size_t)(bt0 + 0) * C_ + c0 + lane);
    float z1 = io<ST>::ld(XW + (size_t)(bt0 + 1) * C_ + c0 + lane);
    float z2 = io<ST>::ld(XW + (size_t)(bt0 + 2) * C_ + c0 + lane);
    float z3 = io<ST>::ld(XW + (size_t)(bt0 + 3) * C_ + c0 + lane);
    if (ch + 1 < 32) {
#pragma unroll
      for (int q = 0; q < 4; ++q) {
        int idx = q * 256 + tid;
        int cc = idx >> 4;
        int j4 = (idx & 15) * 4;
        *(float4*)&w1s[buf ^ 1][cc * 64 + j4] =
            *(const float4*)&DW1[(size_t)(c0 + 64 + cc) * 64 + j4];
      }
    }
#pragma unroll
    for (int l = 0; l < 64; ++l) {
      float wa = w1s[buf][l * 64 + lane];
      acc[0] = fmaf(bcast(z0, l), wa, acc[0]);
      acc[1] = fmaf(bcast(z1, l), wa, acc[1]);
      acc[2] = fmaf(bcast(z2, l), wa, acc[2]);
      acc[3] = fmaf(bcast(z3, l), wa, acc[3]);
    }
    __syncthreads();
  }
#pragma unroll
  for (int tk = 0; tk < 4; ++tk)
    D1[(size_t)(bt0 + tk) * 64 + lane] = tanhf(acc[tk]);
}

// ---------------- K4: DEC = exp(-exp(time_decay + D1 @ DW2)) ----------------
template <typename ST>
static __global__ __launch_bounds__(256) void k4_decay(
    const float* __restrict__ D1, const float* __restrict__ DW2,
    const float* __restrict__ td, ST* __restrict__ DEC) {
  int cb = blockIdx.x & 7;
  int tb = blockIdx.x >> 3;
  int c = cb * 256 + threadIdx.x;
  int bt0 = tb * 16;
  float w2r[64];
#pragma unroll
  for (int k = 0; k < 64; ++k) w2r[k] = DW2[(size_t)k * C_ + c];
  float tdv = td[c];
  for (int tk = 0; tk < 16; ++tk) {
    const float4* d4 = (const float4*)(D1 + (size_t)(bt0 + tk) * 64);
    float a0 = 0.f, a1 = 0.f, a2 = 0.f, a3 = 0.f;
#pragma unroll
    for (int q = 0; q < 16; ++q) {
      float4 dv = d4[q];
      a0 = fmaf(dv.x, w2r[4 * q + 0], a0);
      a1 = fmaf(dv.y, w2r[4 * q + 1], a1);
      a2 = fmaf(dv.z, w2r[4 * q + 2], a2);
      a3 = fmaf(dv.w, w2r[4 * q + 3], a3);
    }
    float w = tdv + (a0 + a1) + (a2 + a3);
    io<ST>::st(DEC + (size_t)(bt0 + tk) * C_ + c, expf(-expf(w)));
  }
}

// ---------------- K5 (fp32 legacy): round-0 register-broadcast version ----------------
static __global__ __launch_bounds__(256) void k5_intra_f32(
    float* XRQ,
    const float* __restrict__ XK, const float* __restrict__ XV,
    const float* __restrict__ DEC, const float* __restrict__ faaaa,
    float* __restrict__ UC, float* __restrict__ DCp, float* __restrict__ Y) {
  int m = threadIdx.x & 63;
  int chunk = blockIdx.x * 4 + (threadIdx.x >> 6);
  int cc = chunk & (NC_ - 1);
  int h = (chunk >> 6) & (H_ - 1);
  int b = chunk >> 11;
  float u = faaaa[h];
  float s[64];
#pragma unroll
  for (int n = 0; n < 64; ++n) s[n] = 0.f;
  float areg = 1.f;
  size_t row = ((size_t)(b * T_ + cc * L_)) * C_ + h * N_;
  for (int t = 0; t < L_; ++t, row += C_) {
    float vm = XV[row + m];
    float wl = DEC[row + m];
    float kl = XK[row + m];
    float rl = XRQ[row + m];
    float dot = rl * kl;
#pragma unroll
    for (int mk = 32; mk >= 1; mk >>= 1) dot += __shfl_xor(dot, mk, 64);
    float y0 = u * vm * dot, y1 = 0.f, y2 = 0.f, y3 = 0.f;
#pragma unroll
    for (int n = 0; n < 64; n += 4) {
      float rn, kn, wn;
      rn = bcast(rl, n + 0); kn = bcast(kl, n + 0); wn = bcast(wl, n + 0);
      y0 = fmaf(rn, s[n + 0], y0); s[n + 0] = fmaf(wn, s[n + 0], kn * vm);
      rn = bcast(rl, n + 1); kn = bcast(kl, n + 1); wn = bcast(wl, n + 1);
      y1 = fmaf(rn, s[n + 1], y1); s[n + 1] = fmaf(wn, s[n + 1], kn * vm);
      rn = bcast(rl, n + 2); kn = bcast(kl, n + 2); wn = bcast(wl, n + 2);
      y2 = fmaf(rn, s[n + 2], y2); s[n + 2] = fmaf(wn, s[n + 2], kn * vm);
      rn = bcast(rl, n + 3); kn = bcast(kl, n + 3); wn = bcast(wl, n + 3);
      y3 = fmaf(rn, s[n + 3], y3); s[n + 3] = fmaf(wn, s[n + 3], kn * vm);
    }
    XRQ[row + m] = rl * areg;
    areg *= wl;
    Y[row + m] = (y0 + y1) + (y2 + y3);
  }
  size_t ucb = (size_t)chunk * (N_ * N_);
#pragma unroll
  for (int n = 0; n < 64; ++n) UC[ucb + (size_t)n * 64 + m] = s[n];
  DCp[(size_t)chunk * N_ + m] = areg;
}

// ---------------- K5 (bf16 packed + clamped prefetch) ----------------
static __global__ __launch_bounds__(256) void k5_intra_bf16(
    const u32* __restrict__ RKI, u16* XVRQ,
    const u16* __restrict__ DEC, const float* __restrict__ faaaa,
    u16* __restrict__ UC, float* __restrict__ DCp, float* __restrict__ Y) {
  int m = threadIdx.x & 63;
  int chunk = blockIdx.x * 4 + (threadIdx.x >> 6);
  int cc = chunk & (NC_ - 1);
  int h = (chunk >> 6) & (H_ - 1);
  int b = chunk >> 11;
  float u = faaaa[h];
  float s[64];
#pragma unroll
  for (int n = 0; n < 64; ++n) s[n] = 0.f;
  float areg = 1.f;
  size_t row = ((size_t)(b * T_ + cc * L_)) * C_ + h * N_;
  u32 nrki = RKI[row + m];
  float nvm = io<u16>::ld(XVRQ + row + m);
  float nwl = io<u16>::ld(DEC + row + m);
  u32 nwpk = ((const u32*)(DEC + row))[m & 31];
#pragma unroll 1
  for (int t = 0; t < L_; ++t, row += C_) {
    u32 rki = nrki;
    float vm = nvm;
    float wl = nwl;
    u32 wpk = nwpk;
    size_t nx = (t + 1 < L_) ? row + C_ : row;   // clamped prefetch (last iter: dummy)
    nrki = RKI[nx + m];
    nvm = io<u16>::ld(XVRQ + nx + m);
    nwl = io<u16>::ld(DEC + nx + m);
    nwpk = ((const u32*)(DEC + nx))[m & 31];
    float rl = bflo(rki), kl = bfhi(rki);
    float dot = rl * kl;
#pragma unroll
    for (int mk = 32; mk >= 1; mk >>= 1) dot += __shfl_xor(dot, mk, 64);
    float y0 = u * vm * dot, y1 = 0.f, y2 = 0.f, y3 = 0.f;
#pragma unroll
    for (int i = 0; i < 32; ++i) {
      u32 rk0 = bcast_u(rki, 2 * i);
      u32 rk1 = bcast_u(rki, 2 * i + 1);
      u32 wp  = bcast_u(wpk, i);
      float r0 = bflo(rk0), k0 = bfhi(rk0);
      float r1 = bflo(rk1), k1 = bfhi(rk1);
      float w0 = bflo(wp),  w1 = bfhi(wp);
      int n = 2 * i;
      if (i & 1) {
        y2 = fmaf(r0, s[n], y2);     s[n]     = fmaf(w0, s[n],     k0 * vm);
        y3 = fmaf(r1, s[n + 1], y3); s[n + 1] = fmaf(w1, s[n + 1], k1 * vm);
      } else {
        y0 = fmaf(r0, s[n], y0);     s[n]     = fmaf(w0, s[n],     k0 * vm);
        y1 = fmaf(r1, s[n + 1], y1); s[n + 1] = fmaf(w1, s[n + 1], k1 * vm);
      }
    }
    io<u16>::st(XVRQ + row + m, rl * areg);   // RQ = r * cumdecay (pre-step)
    areg *= wl;
    Y[row + m] = (y0 + y1) + (y2 + y3);
  }
  size_t ucb = (size_t)chunk * (N_ * N_);
#pragma unroll
  for (int n = 0; n < 64; ++n) io<u16>::st(UC + ucb + (size_t)n * 64 + m, s[n]);
  DCp[(size_t)chunk * N_ + m] = areg;
}

// ---------------- K6 (fp32 legacy): inter-chunk state scan ----------------
template <typename ST>
static __global__ __launch_bounds__(256) void k6_scan(
    const float* __restrict__ attn_kv, ST* __restrict__ UC,
    const float* __restrict__ DCp) {
  int msel = blockIdx.x & 3;
  int bh = blockIdx.x >> 2;
  int ml = threadIdx.x & 15;
  int n0 = threadIdx.x >> 4;
  int m = msel * 16 + ml;
  float s[4];
#pragma unroll
  for (int i = 0; i < 4; ++i) {
    int n = n0 + 16 * i;
    s[i] = attn_kv[((size_t)bh * N_ + n) * N_ + m];
  }
  for (int c = 0; c < NC_; ++c) {
    size_t cb = (size_t)bh * NC_ + c;
#pragma unroll
    for (int i = 0; i < 4; ++i) {
      int n = n0 + 16 * i;
      size_t idx = (cb * (size_t)(N_ * N_)) + (size_t)n * 64 + m;
      float uc = io<ST>::ld(UC + idx);
      float dc = DCp[cb * N_ + n];
      io<ST>::st(UC + idx, s[i]);
      s[i] = fmaf(dc, s[i], uc);
    }
  }
}

// ---------------- K6 (bf16, paired): dword scans with prefetch ----------------
// Thread owns (n, m-pair): one u32 load+store per step instead of 4 scalar u16 ops;
// grid 512 blocks (2x parallelism of the old 256).
static __global__ __launch_bounds__(256) void k6_scan_v2(
    const float* __restrict__ attn_kv, u16* __restrict__ UC,
    const float* __restrict__ DCp) {
  int bh = blockIdx.x >> 3;
  int sub = blockIdx.x & 7;
  int tid = threadIdx.x;
  int n = sub * 8 + (tid >> 5);
  int mp = tid & 31;                       // m = 2*mp, 2*mp+1
  float2 s = *(const float2*)(attn_kv + ((size_t)bh * N_ + n) * N_ + 2 * mp);
  u32* UCd = (u32*)UC;
  size_t base = ((size_t)bh * NC_) * 2048 + (size_t)n * 32 + mp;
  u32 nuc = UCd[base];
  float ndc = DCp[((size_t)bh * NC_) * N_ + n];
#pragma unroll 1
  for (int c = 0; c < NC_; ++c) {
    u32 uc = nuc;
    float dc = ndc;
    size_t idx = base + (size_t)c * 2048;
    if (c + 1 < NC_) {
      nuc = UCd[idx + 2048];
      ndc = DCp[((size_t)bh * NC_ + c + 1) * N_ + n];
    }
    u32 pk = (u32)io<u16>::cvt1(s.x) | ((u32)io<u16>::cvt1(s.y) << 16);
    UCd[idx] = pk;                          // state at chunk start (for k7)
    s.x = fmaf(dc, s.x, bflo(uc));
    s.y = fmaf(dc, s.y, bfhi(uc));
  }
}

// ---------------- K7 (fp32 legacy) ----------------
static __global__ __launch_bounds__(256) void k7_state_f32(
    const float* __restrict__ RQ, const float* __restrict__ UC,
    float* __restrict__ Y) {
  int m = threadIdx.x & 63;
  int chunk = blockIdx.x * 4 + (threadIdx.x >> 6);
  int cc = chunk & (NC_ - 1);
  int h = (chunk >> 6) & (H_ - 1);
  int b = chunk >> 11;
  float sc[64];
  size_t ucb = (size_t)chunk * (N_ * N_);
#pragma unroll
  for (int n = 0; n < 64; ++n) sc[n] = UC[ucb + (size_t)n * 64 + m];
  size_t row = ((size_t)(b * T_ + cc * L_)) * C_ + h * N_;
  for (int t = 0; t < L_; ++t, row += C_) {
    float ql = RQ[row + m];
    float y0 = Y[row + m], y1 = 0.f, y2 = 0.f, y3 = 0.f;
#pragma unroll
    for (int n = 0; n < 64; n += 4) {
      y0 = fmaf(bcast(ql, n + 0), sc[n + 0], y0);
      y1 = fmaf(bcast(ql, n + 1), sc[n + 1], y1);
      y2 = fmaf(bcast(ql, n + 2), sc[n + 2], y2);
      y3 = fmaf(bcast(ql, n + 3), sc[n + 3], y3);
    }
    Y[row + m] = (y0 + y1) + (y2 + y3);
  }
}

// ---------------- K7 (bf16, MFMA): Y += RQ(64x64) @ S0(64x64) per chunk ----------------
static __global__ __launch_bounds__(256) void k7_mfma(
    const u16* __restrict__ RQ, const u16* __restrict__ UC,
    float* __restrict__ Y) {
  __shared__ u16 st[64][64];   // st[m][n ^ ((m&7)<<3)] = S0[n][m]
  int tid = threadIdx.x;
  int chunk = blockIdx.x;
  int cc = chunk & (NC_ - 1);
  int h = (chunk >> 6) & (H_ - 1);
  int b = chunk >> 11;
  const u16* S0 = UC + (size_t)chunk * (N_ * N_);
  {
    int n = tid >> 2;
    int m0 = (tid & 3) << 4;
#pragma unroll
    for (int j = 0; j < 16; ++j) {
      int m = m0 + j;
      st[m][n ^ ((m & 7) << 3)] = S0[n * 64 + m];
    }
  }
  __syncthreads();
  int lane = tid & 63;
  int wv = tid >> 6;
  int trow = lane & 15;
  int kg = lane >> 4;
  int t0 = wv << 4;
  size_t arow = ((size_t)(b * T_ + cc * L_ + t0 + trow)) * C_ + h * N_;
  bf16x8 a0 = *(const bf16x8*)(RQ + arow + kg * 8);
  bf16x8 a1 = *(const bf16x8*)(RQ + arow + 32 + kg * 8);
#pragma unroll
  for (int ct = 0; ct < 4; ++ct) {
    int col = ct * 16 + trow;
    int sw = (col & 7) << 3;
    bf16x8 b0 = *(const bf16x8*)&st[col][(kg * 8) ^ sw];
    bf16x8 b1 = *(const bf16x8*)&st[col][(32 + kg * 8) ^ sw];
    f32x4 c = {0.f, 0.f, 0.f, 0.f};
    c = __builtin_amdgcn_mfma_f32_16x16x32_bf16(a0, b0, c, 0, 0, 0);
    c = __builtin_amdgcn_mfma_f32_16x16x32_bf16(a1, b1, c, 0, 0, 0);
    size_t ybase = ((size_t)(b * T_ + cc * L_ + t0 + kg * 4)) * C_ + h * N_ + ct * 16 + trow;
#pragma unroll
    for (int rg = 0; rg < 4; ++rg)
      Y[ybase + (size_t)rg * C_] += c[rg];
  }
}

// ---------------- host ----------------
static void run_f32(void* const* d_in, void* d_out, void* d_ws, hipStream_t stream) {
  const float* hidden = (const float*)d_in[0];
  const float* attn_x = (const float*)d_in[1];
  const float* attn_kv = (const float*)d_in[2];
  const float* maa_x = (const float*)d_in[4];
  const float* maa_w = (const float*)d_in[5];
  const float* maa_k = (const float*)d_in[6];
  const float* maa_v = (const float*)d_in[7];
  const float* maa_r = (const float*)d_in[8];
  const float* W1 = (const float*)d_in[10];
  const float* W2 = (const float*)d_in[11];
  const float* tdec = (const float*)d_in[12];
  const float* DW1 = (const float*)d_in[13];
  const float* DW2 = (const float*)d_in[14];
  const float* faaaa = (const float*)d_in[15];

  const size_t BIG = (size_t)BT_ * C_;
  char* p = (char*)d_ws;
  float* A   = (float*)p; p += BIG * 4;
  float* XK  = (float*)p; p += BIG * 4;
  float* XV  = (float*)p; p += BIG * 4;
  float* XRQ = (float*)p; p += BIG * 4;
  float* UC  = (float*)p; p += BIG * 4;
  float* P   = (float*)p; p += (size_t)BT_ * 128 * 4;
  float* D1  = (float*)p; p += (size_t)BT_ * 64 * 4;
  float* DCp = (float*)p;
  float* Y = (float*)d_out;

  k0_z<float>    <<<16384, 256, 0, stream>>>(hidden, attn_x, maa_x, A);
  k1_p<float>    <<<BT_ / 16, 256, 0, stream>>>(A, W1, P);
  k2_mix_f32     <<<(BT_ / 16) * 8, 256, 0, stream>>>(hidden, attn_x, P, W2,
                                                      maa_w, maa_k, maa_v, maa_r,
                                                      A, XK, XV, XRQ);
  k3_d1<float>   <<<BT_ / 16, 256, 0, stream>>>(A, DW1, D1);
  k4_decay<float><<<(BT_ / 16) * 8, 256, 0, stream>>>(D1, DW2, tdec, A);
  k5_intra_f32   <<<B_ * H_ * NC_ / 4, 256, 0, stream>>>(XRQ, XK, XV, A, faaaa,
                                                         UC, DCp, Y);
  k6_scan<float> <<<B_ * H_ * 4, 256, 0, stream>>>(attn_kv, UC, DCp);
  k7_state_f32   <<<B_ * H_ * NC_ / 4, 256, 0, stream>>>(XRQ, UC, Y);
}

static void run_bf16(void* const* d_in, void* d_out, void* d_ws, hipStream_t stream) {
  const float* hidden = (const float*)d_in[0];
  const float* attn_x = (const float*)d_in[1];
  const float* attn_kv = (const float*)d_in[2];
  const float* maa_x = (const float*)d_in[4];
  const float* maa_w = (const float*)d_in[5];
  const float* maa_k = (const float*)d_in[6];
  const float* maa_v = (const float*)d_in[7];
  const float* maa_r = (const float*)d_in[8];
  const float* W1 = (const float*)d_in[10];
  const float* W2 = (const float*)d_in[11];
  const float* tdec = (const float*)d_in[12];
  const float* DW1 = (const float*)d_in[13];
  const float* DW2 = (const float*)d_in[14];
  const float* faaaa = (const float*)d_in[15];

  const size_t BIG = (size_t)BT_ * C_;
  char* p = (char*)d_ws;
  u16* A    = (u16*)p; p += BIG * 2;         // Z -> XW -> DEC
  u32* RKI  = (u32*)p; p += BIG * 4;         // (k<<16)|r packed
  u16* XVRQ = (u16*)p; p += BIG * 2;         // XV, overwritten by RQ in k5
  u16* UC   = (u16*)p; p += BIG * 2;
  float* P   = (float*)p; p += (size_t)BT_ * 128 * 4;
  float* D1  = (float*)p; p += (size_t)BT_ * 64 * 4;
  float* DCp = (float*)p;
  float* Y = (float*)d_out;
  // Scratch aliasing: W1T (512 KB) lives in the D1 region (D1 written later by k3);
  // DW1T (256 KB) lives in the DCp region (DCp written later by k5). Zero extra ws.
  u16* W1T  = (u16*)D1;
  u16* DW1T = (u16*)DCp;

  wt_prep      <<<96, 256, 0, stream>>>(W1, DW1, W1T, DW1T);
  k0_z<u16>    <<<16384, 256, 0, stream>>>(hidden, attn_x, maa_x, A);
  k1_mfma      <<<BT_ / 16, 256, 0, stream>>>(A /*Z*/, W1T, P);
  k2_mix_bf16  <<<(BT_ / 16) * 8, 256, 0, stream>>>(hidden, attn_x, P, W2,
                                                    maa_w, maa_k, maa_v, maa_r,
                                                    A, RKI, XVRQ);
  k3_mfma      <<<BT_ / 16, 256, 0, stream>>>(A /*XW*/, DW1T, D1);
  k4_decay<u16><<<(BT_ / 16) * 8, 256, 0, stream>>>(D1, DW2, tdec, A);
  k5_intra_bf16<<<B_ * H_ * NC_ / 4, 256, 0, stream>>>(RKI, XVRQ, A, faaaa,
                                                       UC, DCp, Y);
  k6_scan_v2   <<<B_ * H_ * 8, 256, 0, stream>>>(attn_kv, UC, DCp);
  k7_mfma      <<<B_ * H_ * NC_, 256, 0, stream>>>(XVRQ, UC, Y);
}

extern "C" void kernel_launch(void* const* d_in, const int* in_sizes, int n_in,
                              void* d_out, int out_size, void* d_ws, size_t ws_size,
                              hipStream_t stream) {
  const size_t BIG = (size_t)BT_ * C_;
  const size_t small = (size_t)BT_ * 128 * 4 + (size_t)BT_ * 64 * 4 +
                       (size_t)B_ * H_ * NC_ * N_ * 4;
  const size_t need_f32 = BIG * 4 * 5 + small;   // ~343 MB
  if (ws_size >= need_f32)
    run_f32(d_in, d_out, d_ws, stream);
  else
    run_bf16(d_in, d_out, d_ws, stream);         // bf16 storage + packed RKI, ~175 MB
}